// Round 1
// 3641.990 us; speedup vs baseline: 1.2540x; 1.2540x over previous
//
#include <hip/hip_runtime.h>
#include <math.h>

// ---- problem constants ----
constexpr int kV  = 16384;
constexpr int kD  = 768;
constexpr int kH  = 12;
constexpr int kDH = 64;
constexpr int kL  = 2;
constexpr int kF  = 3072;
constexpr int kC  = 64;     // chunk length
constexpr int kNR = 32;     // NB/2 rotations
constexpr int kNB = 64;     // number of buckets
constexpr int kB  = 2;
constexpr int kS  = 2048;
constexpr int kNC = kS / kC;  // 32 chunks

// ============================================================
// x = emb[ids] + pos_emb
// ============================================================
__global__ void embed_kernel(const int* __restrict__ ids, const float* __restrict__ emb,
                             const float* __restrict__ pos, float* __restrict__ x) {
    int row = blockIdx.x;            // b*S + s
    int s = row % kS;
    int id = ids[row];
    for (int d = threadIdx.x; d < kD; d += blockDim.x)
        x[(size_t)row * kD + d] = emb[(size_t)id * kD + d] + pos[(size_t)s * kD + d];
}

// ============================================================
// LayerNorm: y = (x-m)/sqrt(var+1e-12)*g + b   (row = 768)
// ============================================================
__global__ __launch_bounds__(256) void ln_kernel(const float* __restrict__ X,
                                                 const float* __restrict__ g,
                                                 const float* __restrict__ b,
                                                 float* __restrict__ Y) {
    int row = blockIdx.x;
    size_t base = (size_t)row * kD;
    int tid = threadIdx.x;
    float vals[3];
    float s = 0.f, s2 = 0.f;
    int i = 0;
    for (int d = tid; d < kD; d += 256, ++i) {
        float v = X[base + d];
        vals[i] = v; s += v; s2 += v * v;
    }
    for (int m = 32; m >= 1; m >>= 1) {
        s  += __shfl_xor(s,  m, 64);
        s2 += __shfl_xor(s2, m, 64);
    }
    __shared__ float red[2][4];
    int wid = tid >> 6, lane = tid & 63;
    if (lane == 0) { red[0][wid] = s; red[1][wid] = s2; }
    __syncthreads();
    float ts  = red[0][0] + red[0][1] + red[0][2] + red[0][3];
    float ts2 = red[1][0] + red[1][1] + red[1][2] + red[1][3];
    float mean = ts / kD;
    float var  = ts2 / kD - mean * mean;
    float rstd = 1.0f / sqrtf(var + 1e-12f);
    i = 0;
    for (int d = tid; d < kD; d += 256, ++i)
        Y[base + d] = (vals[i] - mean) * rstd * g[d] + b[d];
}

// ============================================================
// Generic SGEMM: C[M,N] = A[M,K] @ B[K,N] (+bias) (gelu?) (+residual)
// 64x64 tile / block(256), 4x4 micro-tile, K-step 16
// ============================================================
__global__ __launch_bounds__(256) void gemm_kernel(const float* __restrict__ A,
                                                   const float* __restrict__ Bm,
                                                   const float* __restrict__ bias,
                                                   const float* __restrict__ R,
                                                   float* __restrict__ Cm,
                                                   int M, int N, int K, int dogelu) {
    __shared__ float As[16][68];   // [kk][m], padded row -> 16B aligned
    __shared__ float Bs[16][68];   // [kk][n]
    int tid = threadIdx.x;
    int tx = tid & 15, ty = tid >> 4;
    int m0 = blockIdx.y << 6, n0 = blockIdx.x << 6;
    float acc[4][4] = {{0.f}};
    int aM = tid >> 2;             // (tid*4)/16
    int aK = (tid & 3) << 2;       // (tid*4)%16
    int bK = tid >> 4;             // (tid*4)/64
    int bN = (tid & 15) << 2;      // (tid*4)%64
    for (int k0 = 0; k0 < K; k0 += 16) {
        float4 a4 = *(const float4*)(A + (size_t)(m0 + aM) * K + k0 + aK);
        As[aK + 0][aM] = a4.x; As[aK + 1][aM] = a4.y;
        As[aK + 2][aM] = a4.z; As[aK + 3][aM] = a4.w;
        float4 b4 = *(const float4*)(Bm + (size_t)(k0 + bK) * N + n0 + bN);
        Bs[bK][bN + 0] = b4.x; Bs[bK][bN + 1] = b4.y;
        Bs[bK][bN + 2] = b4.z; Bs[bK][bN + 3] = b4.w;
        __syncthreads();
#pragma unroll
        for (int kk = 0; kk < 16; ++kk) {
            float a[4], bb[4];
#pragma unroll
            for (int i = 0; i < 4; ++i) a[i] = As[kk][ty * 4 + i];
#pragma unroll
            for (int j = 0; j < 4; ++j) bb[j] = Bs[kk][tx * 4 + j];
#pragma unroll
            for (int i = 0; i < 4; ++i)
#pragma unroll
                for (int j = 0; j < 4; ++j)
                    acc[i][j] += a[i] * bb[j];
        }
        __syncthreads();
    }
#pragma unroll
    for (int i = 0; i < 4; ++i) {
        int m = m0 + ty * 4 + i;
#pragma unroll
        for (int j = 0; j < 4; ++j) {
            int n = n0 + tx * 4 + j;
            float vv = acc[i][j];
            if (bias) vv += bias[n];
            if (dogelu) {
                float u = 0.7978845608028654f * (vv + 0.044715f * vv * vv * vv);
                vv = 0.5f * vv * (1.f + tanhf(u));
            }
            if (R) vv += R[(size_t)m * N + n];
            Cm[(size_t)m * N + n] = vv;
        }
    }
}

// ============================================================
// bf16x3 split-precision MFMA GEMM: C = A @ B (+bias), fp32 in/out.
// A,B are split on the fly into bf16 hi+lo; accumulate
// ah*bh + ah*bl + al*bh in fp32 MFMA (drop al*bl, rel err ~2^-16).
// 128x128 tile, BK=32, 4 waves (2x2), mfma_f32_16x16x32_bf16,
// 4x4 fragments per wave. LDS rows padded to 40 shorts (80B) so
// 16-lane b128 fragment reads stride 20 banks -> <=2-way (free).
// Requires M%128==0, N%128==0, K%32==0.
// ============================================================
typedef __attribute__((ext_vector_type(8))) short bf16x8;
typedef __attribute__((ext_vector_type(4))) float f32x4;
typedef __attribute__((ext_vector_type(4))) unsigned short us4;

__device__ __forceinline__ unsigned short f2bf(float f) {
    unsigned u = __float_as_uint(f);
    u += 0x7fffu + ((u >> 16) & 1u);      // round-to-nearest-even
    return (unsigned short)(u >> 16);
}
__device__ __forceinline__ float bf2f(unsigned short h) {
    return __uint_as_float(((unsigned)h) << 16);
}

__global__ __launch_bounds__(256) void gemm_mfma3_kernel(const float* __restrict__ A,
                                                         const float* __restrict__ Bm,
                                                         const float* __restrict__ bias,
                                                         float* __restrict__ Cm,
                                                         int M, int N, int K) {
    __shared__ unsigned short Ah[128][40], Al[128][40];   // [m][k], k contiguous
    __shared__ unsigned short Bh[128][40], Bl[128][40];   // [n][k], k contiguous
    int tid = threadIdx.x;
    int m0 = blockIdx.y << 7, n0 = blockIdx.x << 7;
    int lane = tid & 63, wid = tid >> 6;
    int wm = wid >> 1, wn = wid & 1;      // 2x2 wave grid, wave tile 64x64
    int lr = lane & 15, lg = lane >> 4;   // fragment row/col & k-group

    f32x4 acc[4][4] = {};

    // staging assignment
    int aRow = tid >> 3;               // 0..31 (x4 passes -> 128 rows)
    int aK4  = (tid & 7) << 2;         // k offset 0..28 step 4
    int bN   = tid & 127;              // 0..127
    int bK0  = (tid >> 7) << 4;        // 0 or 16

    for (int k0 = 0; k0 < K; k0 += 32) {
        // ---- stage A tile (128x32 fp32 -> bf16 hi/lo), float4 loads ----
#pragma unroll
        for (int rp = 0; rp < 4; ++rp) {
            int row = aRow + rp * 32;
            float4 a4 = *(const float4*)(A + (size_t)(m0 + row) * K + k0 + aK4);
            float f[4] = {a4.x, a4.y, a4.z, a4.w};
            us4 h4, l4;
#pragma unroll
            for (int c = 0; c < 4; ++c) {
                unsigned short h = f2bf(f[c]);
                h4[c] = h;
                l4[c] = f2bf(f[c] - bf2f(h));
            }
            *(us4*)(&Ah[row][aK4]) = h4;   // 8B write, aligned
            *(us4*)(&Al[row][aK4]) = l4;
        }
        // ---- stage B tile (32x128 fp32 -> bf16 hi/lo, transposed to [n][k]) ----
        {
            unsigned short hb[16], lb[16];
#pragma unroll
            for (int j = 0; j < 16; ++j) {
                float f = Bm[(size_t)(k0 + bK0 + j) * N + n0 + bN];
                unsigned short h = f2bf(f);
                hb[j] = h;
                lb[j] = f2bf(f - bf2f(h));
            }
#pragma unroll
            for (int q = 0; q < 4; ++q) {
                us4 h4, l4;
#pragma unroll
                for (int c = 0; c < 4; ++c) { h4[c] = hb[q * 4 + c]; l4[c] = lb[q * 4 + c]; }
                *(us4*)(&Bh[bN][bK0 + q * 4]) = h4;
                *(us4*)(&Bl[bN][bK0 + q * 4]) = l4;
            }
        }
        __syncthreads();
        // ---- fragments: 8 contiguous bf16 per lane (k = lg*8 + j) ----
        bf16x8 fah[4], fal[4], fbh[4], fbl[4];
#pragma unroll
        for (int i = 0; i < 4; ++i) {
            fah[i] = *(const bf16x8*)(&Ah[wm * 64 + i * 16 + lr][lg * 8]);
            fal[i] = *(const bf16x8*)(&Al[wm * 64 + i * 16 + lr][lg * 8]);
            fbh[i] = *(const bf16x8*)(&Bh[wn * 64 + i * 16 + lr][lg * 8]);
            fbl[i] = *(const bf16x8*)(&Bl[wn * 64 + i * 16 + lr][lg * 8]);
        }
#pragma unroll
        for (int i = 0; i < 4; ++i)
#pragma unroll
            for (int j = 0; j < 4; ++j) {
                acc[i][j] = __builtin_amdgcn_mfma_f32_16x16x32_bf16(fah[i], fbh[j], acc[i][j], 0, 0, 0);
                acc[i][j] = __builtin_amdgcn_mfma_f32_16x16x32_bf16(fah[i], fbl[j], acc[i][j], 0, 0, 0);
                acc[i][j] = __builtin_amdgcn_mfma_f32_16x16x32_bf16(fal[i], fbh[j], acc[i][j], 0, 0, 0);
            }
        __syncthreads();
    }
    // ---- epilogue: D[row=(lg)*4+reg (+i*16), col=lr (+j*16)] ----
#pragma unroll
    for (int j = 0; j < 4; ++j) {
        int col = n0 + wn * 64 + j * 16 + lr;
        float bv = bias ? bias[col] : 0.f;
#pragma unroll
        for (int i = 0; i < 4; ++i) {
            int rowb = m0 + wm * 64 + i * 16 + lg * 4;
#pragma unroll
            for (int r = 0; r < 4; ++r)
                Cm[(size_t)(rowb + r) * N + col] = acc[i][j][r] + bv;
        }
    }
}

// ============================================================
// LSH bucketing: rotated = qk . rot ; bucket = argmax([r,-r])
// one thread per (b,h,s); double accumulation for tie robustness
// ============================================================
__global__ void bucket_kernel(const float* __restrict__ qk, const float* __restrict__ rot,
                              int* __restrict__ buckets) {
    int t = blockIdx.x * 256 + threadIdx.x;
    if (t >= kB * kH * kS) return;
    int b = t / (kH * kS);
    int h = (t / kS) % kH;
    int s = t % kS;
    const float* q  = qk + ((size_t)(b * kS + s)) * kD + h * kDH;
    const float* rr = rot + (size_t)h * kDH * kNR;
    float rv[kNR];
    for (int r = 0; r < kNR; ++r) {
        double acc = 0.0;
        for (int d = 0; d < kDH; ++d)
            acc += (double)q[d] * (double)rr[d * kNR + r];
        rv[r] = (float)acc;
    }
    float best = -INFINITY; int bi = 0;
    for (int idx = 0; idx < 2 * kNR; ++idx) {
        float v = (idx < kNR) ? rv[idx] : -rv[idx - kNR];
        if (v > best) { best = v; bi = idx; }   // first occurrence of max
    }
    buckets[t] = bi;
}

// ============================================================
// Stable counting sort of positions by bucket, per (b,h)
// order[rank] = s  (rank = ahead-in-smaller-buckets + earlier-equal)
// ============================================================
__global__ __launch_bounds__(256) void sort_kernel(const int* __restrict__ buckets,
                                                   int* __restrict__ order) {
    __shared__ int sb[kS];
    __shared__ int hist[kNB];
    __shared__ int offs[kNB];
    int bh = blockIdx.x;
    const int* bk = buckets + (size_t)bh * kS;
    for (int s = threadIdx.x; s < kS; s += 256) sb[s] = bk[s];
    for (int i = threadIdx.x; i < kNB; i += 256) hist[i] = 0;
    __syncthreads();
    for (int s = threadIdx.x; s < kS; s += 256) atomicAdd(&hist[sb[s]], 1);
    __syncthreads();
    if (threadIdx.x == 0) {
        int run = 0;
        for (int k = 0; k < kNB; ++k) { offs[k] = run; run += hist[k]; }
    }
    __syncthreads();
    for (int s = threadIdx.x; s < kS; s += 256) {
        int bkt = sb[s];
        int cnt = 0;
        for (int t = 0; t < s; ++t) cnt += (sb[t] == bkt) ? 1 : 0;
        order[(size_t)bh * kS + offs[bkt] + cnt] = s;
    }
}

// ============================================================
// Gather sorted qk/v, L2-normalize keys, gather buckets & mask.
// One wave (64 lanes) per sorted row.
// ============================================================
__global__ __launch_bounds__(256) void gather_kernel(const float* __restrict__ qk,
                                                     const float* __restrict__ v,
                                                     const int* __restrict__ buckets,
                                                     const int* __restrict__ amask,
                                                     const int* __restrict__ order,
                                                     float* __restrict__ sqk,
                                                     float* __restrict__ skey,
                                                     float* __restrict__ sv,
                                                     int* __restrict__ sb,
                                                     int* __restrict__ sm) {
    int wid = threadIdx.x >> 6, lane = threadIdx.x & 63;
    int i = blockIdx.x * 4 + wid;         // flat (b*H+h)*S + is
    int b  = i / (kH * kS);
    int h  = (i / kS) % kH;
    int j  = order[i];
    size_t src = ((size_t)(b * kS + j)) * kD + h * kDH + lane;
    float qv = qk[src];
    float vv = v[src];
    float ss = qv * qv;
    for (int m = 32; m >= 1; m >>= 1) ss += __shfl_xor(ss, m, 64);
    float nrm = sqrtf(ss) + 1e-6f;
    size_t o = (size_t)i * kDH + lane;
    sqk[o]  = qv;
    skey[o] = qv / nrm;
    sv[o]   = vv;
    if (lane == 0) {
        sb[i] = buckets[(size_t)(b * kH + h) * kS + j];
        sm[i] = amask[b * kS + j];
    }
}

// ============================================================
// Chunked LSH attention with 1-chunk lookback (wrapping).
// Block per (b,h,chunk). Output scattered to unsorted layout.
// ============================================================
__global__ __launch_bounds__(256) void attn_kernel(const float* __restrict__ sqk,
                                                   const float* __restrict__ skey,
                                                   const float* __restrict__ sv,
                                                   const int* __restrict__ sb,
                                                   const int* __restrict__ sm,
                                                   const int* __restrict__ order,
                                                   float* __restrict__ aout) {
    __shared__ float ke[2 * kC][kDH + 1];
    __shared__ float qc[kC][kDH];
    __shared__ int bc[kC], icc[kC], be[2 * kC], me[2 * kC], ie[2 * kC];
    int idx = blockIdx.x;
    int b = idx / (kH * kNC);
    int h = (idx / kNC) % kH;
    int n = idx % kNC;
    int prev = (n + kNC - 1) % kNC;
    size_t bhrow = (size_t)(b * kH + h) * kS;
    size_t kbase = bhrow * kDH;
    int tid = threadIdx.x;
    for (int t = tid; t < 2 * kC * kDH; t += 256) {
        int k = t >> 6, d = t & 63;
        int chunk = (k < kC) ? prev : n;
        int krow  = (k < kC) ? k : k - kC;
        ke[k][d] = skey[kbase + ((size_t)(chunk * kC + krow)) * kDH + d];
    }
    for (int t = tid; t < kC * kDH; t += 256) {
        int c = t >> 6, d = t & 63;
        qc[c][d] = sqk[kbase + ((size_t)(n * kC + c)) * kDH + d];
    }
    if (tid < kC) {
        bc[tid]  = sb[bhrow + n * kC + tid];
        icc[tid] = order[bhrow + n * kC + tid];
    }
    for (int t = tid; t < 2 * kC; t += 256) {
        int chunk = (t < kC) ? prev : n;
        int krow  = (t < kC) ? t : t - kC;
        be[t] = sb[bhrow + chunk * kC + krow];
        me[t] = sm[bhrow + chunk * kC + krow];
        ie[t] = order[bhrow + chunk * kC + krow];
    }
    __syncthreads();
    int wid = tid >> 6, lane = tid & 63;
    const float* vprev = sv + kbase + (size_t)prev * kC * kDH;
    const float* vcur  = sv + kbase + (size_t)n * kC * kDH;
    for (int it = 0; it < kC / 4; ++it) {
        int c = it * 4 + wid;
        int col0 = lane, col1 = kC + lane;
        float d0 = 0.f, d1 = 0.f;
#pragma unroll 8
        for (int d = 0; d < kDH; ++d) {
            float q = qc[c][d];
            d0 += q * ke[col0][d];
            d1 += q * ke[col1][d];
        }
        float v0 = d0 * 0.125f, v1 = d1 * 0.125f;   // / sqrt(64)
        int bcc = bc[c], icv = icc[c];
        if (bcc != be[col0] || me[col0] <= 0) v0 = -1e9f;
        if (bcc != be[col1] || me[col1] <= 0) v1 = -1e9f;
        if (icv == ie[col0]) v0 = -1e5f;            // self-mask last (overrides)
        if (icv == ie[col1]) v1 = -1e5f;
        float mx = fmaxf(v0, v1);
        for (int m = 32; m >= 1; m >>= 1) mx = fmaxf(mx, __shfl_xor(mx, m, 64));
        float e0 = expf(v0 - mx), e1 = expf(v1 - mx);
        float sum = e0 + e1;
        for (int m = 32; m >= 1; m >>= 1) sum += __shfl_xor(sum, m, 64);
        float p0 = e0 / sum, p1 = e1 / sum;
        float acc = 0.f;
        for (int k = 0; k < kC; ++k) {
            float a = __shfl(p0, k, 64);            // broadcast -> uniform branch
            if (a != 0.f) acc += a * vprev[(size_t)k * kDH + lane];
        }
        for (int k = 0; k < kC; ++k) {
            float a = __shfl(p1, k, 64);
            if (a != 0.f) acc += a * vcur[(size_t)k * kDH + lane];
        }
        aout[((size_t)(b * kS + icv)) * kD + h * kDH + lane] = acc;  // scatter = unsort
    }
}

// ============================================================
// host launcher
// ============================================================
extern "C" void kernel_launch(void* const* d_in, const int* in_sizes, int n_in,
                              void* d_out, int out_size, void* d_ws, size_t ws_size,
                              hipStream_t stream) {
    const int*   ids   = (const int*)d_in[0];
    const int*   amask = (const int*)d_in[1];
    const float* emb   = (const float*)d_in[2];
    const float* pos   = (const float*)d_in[3];
    const float* rot   = (const float*)d_in[4];
    const float* Wqk   = (const float*)d_in[5];
    const float* Wv    = (const float*)d_in[6];
    const float* Wo    = (const float*)d_in[7];
    const float* ln1g  = (const float*)d_in[8];
    const float* ln1b  = (const float*)d_in[9];
    const float* ln2g  = (const float*)d_in[10];
    const float* ln2b  = (const float*)d_in[11];
    const float* W1    = (const float*)d_in[12];
    const float* b1    = (const float*)d_in[13];
    const float* W2    = (const float*)d_in[14];
    const float* b2    = (const float*)d_in[15];
    const float* lnfg  = (const float*)d_in[16];
    const float* lnfb  = (const float*)d_in[17];
    const float* Wlm   = (const float*)d_in[18];
    const float* blm   = (const float*)d_in[19];
    float* out = (float*)d_out;

    const size_t NX  = (size_t)kB * kS * kD;    // 3,145,728 floats
    const size_t NBH = (size_t)kB * kH * kS;    // 49,152

    // Large fp32 scratch lives in d_out (256 MB; final GEMM rewrites all of it
    // and reads only xn/Wlm). Only xn + int arrays use d_ws (~13.4 MB).
    float* x     = out;            // [B,S,D]
    float* qk    = out + 1 * NX;   // [B,S,H*DH]
    float* v     = out + 2 * NX;
    float* sqk   = out + 3 * NX;   // sorted, [B,H,S,DH]
    float* skey  = out + 4 * NX;
    float* sv    = out + 5 * NX;
    float* aoutb = out + 6 * NX;   // attention output, unsorted [B,S,D]
    float* h1    = out + 7 * NX;   // FFN intermediate [B,S,F] = 4*NX
    float* xn    = (float*)d_ws;   // layernorm output [B,S,D]
    int* ibase   = (int*)((float*)d_ws + NX);
    int* buckets = ibase;
    int* order   = ibase + NBH;
    int* sb      = ibase + 2 * NBH;
    int* smv     = ibase + 3 * NBH;

    const int rows = kB * kS;  // 4096

    embed_kernel<<<rows, 256, 0, stream>>>(ids, emb, pos, x);

    for (int l = 0; l < kL; ++l) {
        ln_kernel<<<rows, 256, 0, stream>>>(x, ln1g + l * kD, ln1b + l * kD, xn);
        gemm_kernel<<<dim3(kD / 64, rows / 64), 256, 0, stream>>>(
            xn, Wqk + (size_t)l * kD * kD, nullptr, nullptr, qk, rows, kD, kD, 0);
        gemm_kernel<<<dim3(kD / 64, rows / 64), 256, 0, stream>>>(
            xn, Wv + (size_t)l * kD * kD, nullptr, nullptr, v, rows, kD, kD, 0);
        bucket_kernel<<<(kB * kH * kS) / 256, 256, 0, stream>>>(
            qk, rot + (size_t)l * kH * kDH * kNR, buckets);
        sort_kernel<<<kB * kH, 256, 0, stream>>>(buckets, order);
        gather_kernel<<<(kB * kH * kS) / 4, 256, 0, stream>>>(
            qk, v, buckets, amask, order, sqk, skey, sv, sb, smv);
        attn_kernel<<<kB * kH * kNC, 256, 0, stream>>>(
            sqk, skey, sv, sb, smv, order, aoutb);
        gemm_kernel<<<dim3(kD / 64, rows / 64), 256, 0, stream>>>(
            aoutb, Wo + (size_t)l * kD * kD, nullptr, x, x, rows, kD, kD, 0);
        ln_kernel<<<rows, 256, 0, stream>>>(x, ln2g + l * kD, ln2b + l * kD, xn);
        gemm_kernel<<<dim3(kF / 64, rows / 64), 256, 0, stream>>>(
            xn, W1 + (size_t)l * kD * kF, b1 + (size_t)l * kF, nullptr, h1, rows, kF, kD, 1);
        gemm_kernel<<<dim3(kD / 64, rows / 64), 256, 0, stream>>>(
            h1, W2 + (size_t)l * kF * kD, b2 + (size_t)l * kD, x, x, rows, kD, kF, 0);
    }

    ln_kernel<<<rows, 256, 0, stream>>>(x, lnfg, lnfb, xn);
    // LM head: bf16x3 split MFMA (post-final-LN, cannot perturb LSH buckets)
    gemm_mfma3_kernel<<<dim3(kV / 128, rows / 128), 256, 0, stream>>>(
        xn, Wlm, blm, out, rows, kV, kD);
}

// Round 2
// 3203.512 us; speedup vs baseline: 1.4256x; 1.1369x over previous
//
#include <hip/hip_runtime.h>
#include <math.h>

// ---- problem constants ----
constexpr int kV  = 16384;
constexpr int kD  = 768;
constexpr int kH  = 12;
constexpr int kDH = 64;
constexpr int kL  = 2;
constexpr int kF  = 3072;
constexpr int kC  = 64;     // chunk length
constexpr int kNR = 32;     // NB/2 rotations
constexpr int kNB = 64;     // number of buckets
constexpr int kB  = 2;
constexpr int kS  = 2048;
constexpr int kNC = kS / kC;  // 32 chunks

typedef __attribute__((ext_vector_type(8))) short bf16x8;
typedef __attribute__((ext_vector_type(4))) float f32x4;
typedef __attribute__((ext_vector_type(4))) unsigned short us4;
typedef __attribute__((ext_vector_type(8))) unsigned short us8;

__device__ __forceinline__ unsigned short f2bf(float f) {
    unsigned u = __float_as_uint(f);
    u += 0x7fffu + ((u >> 16) & 1u);      // round-to-nearest-even
    return (unsigned short)(u >> 16);
}
__device__ __forceinline__ float bf2f(unsigned short h) {
    return __uint_as_float(((unsigned)h) << 16);
}

#define GLOAD_LDS16(gp, lp) __builtin_amdgcn_global_load_lds( \
    (const __attribute__((address_space(1))) unsigned int*)(gp), \
    (__attribute__((address_space(3))) unsigned int*)(lp), 16, 0, 0)

// ============================================================
// x = emb[ids] + pos_emb
// ============================================================
__global__ void embed_kernel(const int* __restrict__ ids, const float* __restrict__ emb,
                             const float* __restrict__ pos, float* __restrict__ x) {
    int row = blockIdx.x;            // b*S + s
    int s = row % kS;
    int id = ids[row];
    for (int d = threadIdx.x; d < kD; d += blockDim.x)
        x[(size_t)row * kD + d] = emb[(size_t)id * kD + d] + pos[(size_t)s * kD + d];
}

// ============================================================
// LayerNorm: y = (x-m)/sqrt(var+1e-12)*g + b   (row = 768)
// ============================================================
__global__ __launch_bounds__(256) void ln_kernel(const float* __restrict__ X,
                                                 const float* __restrict__ g,
                                                 const float* __restrict__ b,
                                                 float* __restrict__ Y) {
    int row = blockIdx.x;
    size_t base = (size_t)row * kD;
    int tid = threadIdx.x;
    float vals[3];
    float s = 0.f, s2 = 0.f;
    int i = 0;
    for (int d = tid; d < kD; d += 256, ++i) {
        float v = X[base + d];
        vals[i] = v; s += v; s2 += v * v;
    }
    for (int m = 32; m >= 1; m >>= 1) {
        s  += __shfl_xor(s,  m, 64);
        s2 += __shfl_xor(s2, m, 64);
    }
    __shared__ float red[2][4];
    int wid = tid >> 6, lane = tid & 63;
    if (lane == 0) { red[0][wid] = s; red[1][wid] = s2; }
    __syncthreads();
    float ts  = red[0][0] + red[0][1] + red[0][2] + red[0][3];
    float ts2 = red[1][0] + red[1][1] + red[1][2] + red[1][3];
    float mean = ts / kD;
    float var  = ts2 / kD - mean * mean;
    float rstd = 1.0f / sqrtf(var + 1e-12f);
    i = 0;
    for (int d = tid; d < kD; d += 256, ++i)
        Y[base + d] = (vals[i] - mean) * rstd * g[d] + b[d];
}

// ============================================================
// fp32 -> bf16 hi/lo split (elementwise, float4 per thread)
// ============================================================
__global__ __launch_bounds__(256) void convsplit_kernel(const float* __restrict__ X,
                                                        unsigned short* __restrict__ H,
                                                        unsigned short* __restrict__ L,
                                                        int n4) {
    int i = blockIdx.x * 256 + threadIdx.x;
    if (i >= n4) return;
    float4 f4 = ((const float4*)X)[i];
    float f[4] = {f4.x, f4.y, f4.z, f4.w};
    us4 h4, l4;
#pragma unroll
    for (int c = 0; c < 4; ++c) {
        unsigned short h = f2bf(f[c]);
        h4[c] = h;
        l4[c] = f2bf(f[c] - bf2f(h));
    }
    ((us4*)H)[i] = h4;
    ((us4*)L)[i] = l4;
}

// ============================================================
// Generic SGEMM: C[M,N] = A[M,K] @ B[K,N] (+bias) (gelu?) (+residual)
// 64x64 tile / block(256), 4x4 micro-tile, K-step 16
// ============================================================
__global__ __launch_bounds__(256) void gemm_kernel(const float* __restrict__ A,
                                                   const float* __restrict__ Bm,
                                                   const float* __restrict__ bias,
                                                   const float* __restrict__ R,
                                                   float* __restrict__ Cm,
                                                   int M, int N, int K, int dogelu) {
    __shared__ float As[16][68];   // [kk][m], padded row -> 16B aligned
    __shared__ float Bs[16][68];   // [kk][n]
    int tid = threadIdx.x;
    int tx = tid & 15, ty = tid >> 4;
    int m0 = blockIdx.y << 6, n0 = blockIdx.x << 6;
    float acc[4][4] = {{0.f}};
    int aM = tid >> 2;             // (tid*4)/16
    int aK = (tid & 3) << 2;       // (tid*4)%16
    int bK = tid >> 4;             // (tid*4)/64
    int bN = (tid & 15) << 2;      // (tid*4)%64
    for (int k0 = 0; k0 < K; k0 += 16) {
        float4 a4 = *(const float4*)(A + (size_t)(m0 + aM) * K + k0 + aK);
        As[aK + 0][aM] = a4.x; As[aK + 1][aM] = a4.y;
        As[aK + 2][aM] = a4.z; As[aK + 3][aM] = a4.w;
        float4 b4 = *(const float4*)(Bm + (size_t)(k0 + bK) * N + n0 + bN);
        Bs[bK][bN + 0] = b4.x; Bs[bK][bN + 1] = b4.y;
        Bs[bK][bN + 2] = b4.z; Bs[bK][bN + 3] = b4.w;
        __syncthreads();
#pragma unroll
        for (int kk = 0; kk < 16; ++kk) {
            float a[4], bb[4];
#pragma unroll
            for (int i = 0; i < 4; ++i) a[i] = As[kk][ty * 4 + i];
#pragma unroll
            for (int j = 0; j < 4; ++j) bb[j] = Bs[kk][tx * 4 + j];
#pragma unroll
            for (int i = 0; i < 4; ++i)
#pragma unroll
                for (int j = 0; j < 4; ++j)
                    acc[i][j] += a[i] * bb[j];
        }
        __syncthreads();
    }
#pragma unroll
    for (int i = 0; i < 4; ++i) {
        int m = m0 + ty * 4 + i;
#pragma unroll
        for (int j = 0; j < 4; ++j) {
            int n = n0 + tx * 4 + j;
            float vv = acc[i][j];
            if (bias) vv += bias[n];
            if (dogelu) {
                float u = 0.7978845608028654f * (vv + 0.044715f * vv * vv * vv);
                vv = 0.5f * vv * (1.f + tanhf(u));
            }
            if (R) vv += R[(size_t)m * N + n];
            Cm[(size_t)m * N + n] = vv;
        }
    }
}

// ============================================================
// bf16x3 split-precision MFMA GEMM (on-the-fly conversion):
// C = A @ B (+bias) (gelu?) (+residual), fp32 in/out.
// 128x128 tile, BK=32, 4 waves (2x2), mfma_f32_16x16x32_bf16.
// Requires M%128==0 (from mbase), N%128==0, K%32==0.
// ============================================================
__global__ __launch_bounds__(256) void gemm_mfma3_kernel(const float* __restrict__ A,
                                                         const float* __restrict__ Bm,
                                                         const float* __restrict__ bias,
                                                         const float* __restrict__ R,
                                                         float* __restrict__ Cm,
                                                         int M, int N, int K,
                                                         int dogelu, int mbase) {
    __shared__ unsigned short Ah[128][40], Al[128][40];   // [m][k], k contiguous
    __shared__ unsigned short Bh[128][40], Bl[128][40];   // [n][k], k contiguous
    int tid = threadIdx.x;
    int m0 = mbase + (blockIdx.y << 7), n0 = blockIdx.x << 7;
    int lane = tid & 63, wid = tid >> 6;
    int wm = wid >> 1, wn = wid & 1;      // 2x2 wave grid, wave tile 64x64
    int lr = lane & 15, lg = lane >> 4;   // fragment row/col & k-group

    f32x4 acc[4][4] = {};

    int aRow = tid >> 3;               // 0..31 (x4 passes -> 128 rows)
    int aK4  = (tid & 7) << 2;         // k offset 0..28 step 4
    int bN   = tid & 127;              // 0..127
    int bK0  = (tid >> 7) << 4;        // 0 or 16

    for (int k0 = 0; k0 < K; k0 += 32) {
#pragma unroll
        for (int rp = 0; rp < 4; ++rp) {
            int row = aRow + rp * 32;
            float4 a4 = *(const float4*)(A + (size_t)(m0 + row) * K + k0 + aK4);
            float f[4] = {a4.x, a4.y, a4.z, a4.w};
            us4 h4, l4;
#pragma unroll
            for (int c = 0; c < 4; ++c) {
                unsigned short h = f2bf(f[c]);
                h4[c] = h;
                l4[c] = f2bf(f[c] - bf2f(h));
            }
            *(us4*)(&Ah[row][aK4]) = h4;
            *(us4*)(&Al[row][aK4]) = l4;
        }
        {
            unsigned short hb[16], lb[16];
#pragma unroll
            for (int j = 0; j < 16; ++j) {
                float f = Bm[(size_t)(k0 + bK0 + j) * N + n0 + bN];
                unsigned short h = f2bf(f);
                hb[j] = h;
                lb[j] = f2bf(f - bf2f(h));
            }
#pragma unroll
            for (int q = 0; q < 4; ++q) {
                us4 h4, l4;
#pragma unroll
                for (int c = 0; c < 4; ++c) { h4[c] = hb[q * 4 + c]; l4[c] = lb[q * 4 + c]; }
                *(us4*)(&Bh[bN][bK0 + q * 4]) = h4;
                *(us4*)(&Bl[bN][bK0 + q * 4]) = l4;
            }
        }
        __syncthreads();
        bf16x8 fah[4], fal[4], fbh[4], fbl[4];
#pragma unroll
        for (int i = 0; i < 4; ++i) {
            fah[i] = *(const bf16x8*)(&Ah[wm * 64 + i * 16 + lr][lg * 8]);
            fal[i] = *(const bf16x8*)(&Al[wm * 64 + i * 16 + lr][lg * 8]);
            fbh[i] = *(const bf16x8*)(&Bh[wn * 64 + i * 16 + lr][lg * 8]);
            fbl[i] = *(const bf16x8*)(&Bl[wn * 64 + i * 16 + lr][lg * 8]);
        }
#pragma unroll
        for (int i = 0; i < 4; ++i)
#pragma unroll
            for (int j = 0; j < 4; ++j) {
                acc[i][j] = __builtin_amdgcn_mfma_f32_16x16x32_bf16(fah[i], fbh[j], acc[i][j], 0, 0, 0);
                acc[i][j] = __builtin_amdgcn_mfma_f32_16x16x32_bf16(fah[i], fbl[j], acc[i][j], 0, 0, 0);
                acc[i][j] = __builtin_amdgcn_mfma_f32_16x16x32_bf16(fal[i], fbh[j], acc[i][j], 0, 0, 0);
            }
        __syncthreads();
    }
#pragma unroll
    for (int j = 0; j < 4; ++j) {
        int col = n0 + wn * 64 + j * 16 + lr;
        float bv = bias ? bias[col] : 0.f;
#pragma unroll
        for (int i = 0; i < 4; ++i) {
            int rowb = m0 + wm * 64 + i * 16 + lg * 4;
#pragma unroll
            for (int r = 0; r < 4; ++r) {
                float vv = acc[i][j][r] + bv;
                if (dogelu) {
                    float u = 0.7978845608028654f * (vv + 0.044715f * vv * vv * vv);
                    vv = 0.5f * vv * (1.f + tanhf(u));
                }
                if (R) vv += R[(size_t)(rowb + r) * N + col];
                Cm[(size_t)(rowb + r) * N + col] = vv;
            }
        }
    }
}

// ============================================================
// LM-head fast GEMM: C[0..3839, 16384] = xn @ Wlm + blm, bf16x3.
// A precomputed as bf16 hi/lo (xnH/xnL). 256x128 tile, BK=32,
// 512 threads (8 waves, 4x2 grid, 64x64 wave tiles).
// A staged via global_load_lds (16B) with pre-swizzled source;
// B converted on the fly into XOR-swizzled [col][k] LDS.
// Swizzle: 64B rows of 4x16B slots; phys_slot = slot ^ ((row>>1)&3)
// -> fragment reads bijectively cover a full 16-row stripe (<=2-way).
// ============================================================
__global__ __launch_bounds__(512) void lmhead_kernel(const unsigned short* __restrict__ AHg,
                                                     const unsigned short* __restrict__ ALg,
                                                     const float* __restrict__ Wlm,
                                                     const float* __restrict__ blm,
                                                     float* __restrict__ Cm) {
    __shared__ unsigned short AH[256 * 32], AL[256 * 32];
    __shared__ unsigned short BH[128 * 32], BL[128 * 32];
    int tid = threadIdx.x;
    int lane = tid & 63, wid = tid >> 6;
    int wm = wid >> 1, wn = wid & 1;       // 4x2 wave grid
    int lr = lane & 15, lg = lane >> 4;
    int m0 = blockIdx.y << 8;              // 256-row tiles (rows < 3840)
    int n0 = blockIdx.x << 7;

    f32x4 acc[4][4] = {};

    // A staging: 2 ops x 1KB per wave per array; op o covers rows 16o..16o+15
    int arow_in = lane >> 2;
    int aphys   = lane & 3;
    int o0 = wid * 2, o1 = wid * 2 + 1;
    int row0 = o0 * 16 + arow_in;
    int row1 = o1 * 16 + arow_in;
    int s0 = aphys ^ ((row0 >> 1) & 3);
    int s1 = aphys ^ ((row1 >> 1) & 3);
    size_t ga0 = (size_t)(m0 + row0) * 768 + s0 * 8;
    size_t ga1 = (size_t)(m0 + row1) * 768 + s1 * 8;

    // B staging: one (col, k-slot) pair per thread
    int bcol = tid & 127;
    int bsl  = tid >> 7;                   // logical k-slot (8 k's each)
    int bphys = bsl ^ ((bcol >> 1) & 3);
    const size_t bstr = 16384;

    for (int k0 = 0; k0 < 768; k0 += 32) {
        GLOAD_LDS16(AHg + ga0 + k0, &AH[o0 * 512]);
        GLOAD_LDS16(AHg + ga1 + k0, &AH[o1 * 512]);
        GLOAD_LDS16(ALg + ga0 + k0, &AL[o0 * 512]);
        GLOAD_LDS16(ALg + ga1 + k0, &AL[o1 * 512]);
        const float* bp = Wlm + (size_t)(k0 + bsl * 8) * bstr + n0 + bcol;
        float f[8];
#pragma unroll
        for (int j = 0; j < 8; ++j) f[j] = bp[(size_t)j * bstr];
        us8 hv, lv;
#pragma unroll
        for (int j = 0; j < 8; ++j) {
            unsigned short h = f2bf(f[j]);
            hv[j] = h;
            lv[j] = f2bf(f[j] - bf2f(h));
        }
        *(us8*)(&BH[bcol * 32 + bphys * 8]) = hv;
        *(us8*)(&BL[bcol * 32 + bphys * 8]) = lv;
        __syncthreads();
        bf16x8 fah[4], fal[4];
#pragma unroll
        for (int i = 0; i < 4; ++i) {
            int ar = wm * 64 + i * 16 + lr;
            int sa = (lg ^ ((ar >> 1) & 3)) * 8;
            fah[i] = *(const bf16x8*)(&AH[ar * 32 + sa]);
            fal[i] = *(const bf16x8*)(&AL[ar * 32 + sa]);
        }
#pragma unroll
        for (int j = 0; j < 4; ++j) {
            int bc = wn * 64 + j * 16 + lr;
            int sb = (lg ^ ((bc >> 1) & 3)) * 8;
            bf16x8 fbh = *(const bf16x8*)(&BH[bc * 32 + sb]);
            bf16x8 fbl = *(const bf16x8*)(&BL[bc * 32 + sb]);
#pragma unroll
            for (int i = 0; i < 4; ++i) {
                acc[i][j] = __builtin_amdgcn_mfma_f32_16x16x32_bf16(fah[i], fbh, acc[i][j], 0, 0, 0);
                acc[i][j] = __builtin_amdgcn_mfma_f32_16x16x32_bf16(fah[i], fbl, acc[i][j], 0, 0, 0);
                acc[i][j] = __builtin_amdgcn_mfma_f32_16x16x32_bf16(fal[i], fbh, acc[i][j], 0, 0, 0);
            }
        }
        __syncthreads();
    }
#pragma unroll
    for (int j = 0; j < 4; ++j) {
        int col = n0 + wn * 64 + j * 16 + lr;
        float bv = blm[col];
#pragma unroll
        for (int i = 0; i < 4; ++i) {
            int rowb = m0 + wm * 64 + i * 16 + lg * 4;
#pragma unroll
            for (int r = 0; r < 4; ++r)
                Cm[(size_t)(rowb + r) * 16384 + col] = acc[i][j][r] + bv;
        }
    }
}

// ============================================================
// LSH bucketing: rotated = qk . rot ; bucket = argmax([r,-r])
// ============================================================
__global__ void bucket_kernel(const float* __restrict__ qk, const float* __restrict__ rot,
                              int* __restrict__ buckets) {
    int t = blockIdx.x * 256 + threadIdx.x;
    if (t >= kB * kH * kS) return;
    int b = t / (kH * kS);
    int h = (t / kS) % kH;
    int s = t % kS;
    const float* q  = qk + ((size_t)(b * kS + s)) * kD + h * kDH;
    const float* rr = rot + (size_t)h * kDH * kNR;
    float rv[kNR];
    for (int r = 0; r < kNR; ++r) {
        double acc = 0.0;
        for (int d = 0; d < kDH; ++d)
            acc += (double)q[d] * (double)rr[d * kNR + r];
        rv[r] = (float)acc;
    }
    float best = -INFINITY; int bi = 0;
    for (int idx = 0; idx < 2 * kNR; ++idx) {
        float v = (idx < kNR) ? rv[idx] : -rv[idx - kNR];
        if (v > best) { best = v; bi = idx; }   // first occurrence of max
    }
    buckets[t] = bi;
}

// ============================================================
// Stable counting sort of positions by bucket, per (b,h)
// ============================================================
__global__ __launch_bounds__(256) void sort_kernel(const int* __restrict__ buckets,
                                                   int* __restrict__ order) {
    __shared__ int sb[kS];
    __shared__ int hist[kNB];
    __shared__ int offs[kNB];
    int bh = blockIdx.x;
    const int* bk = buckets + (size_t)bh * kS;
    for (int s = threadIdx.x; s < kS; s += 256) sb[s] = bk[s];
    for (int i = threadIdx.x; i < kNB; i += 256) hist[i] = 0;
    __syncthreads();
    for (int s = threadIdx.x; s < kS; s += 256) atomicAdd(&hist[sb[s]], 1);
    __syncthreads();
    if (threadIdx.x == 0) {
        int run = 0;
        for (int k = 0; k < kNB; ++k) { offs[k] = run; run += hist[k]; }
    }
    __syncthreads();
    for (int s = threadIdx.x; s < kS; s += 256) {
        int bkt = sb[s];
        int cnt = 0;
        for (int t = 0; t < s; ++t) cnt += (sb[t] == bkt) ? 1 : 0;
        order[(size_t)bh * kS + offs[bkt] + cnt] = s;
    }
}

// ============================================================
// Gather sorted qk/v, L2-normalize keys, gather buckets & mask.
// ============================================================
__global__ __launch_bounds__(256) void gather_kernel(const float* __restrict__ qk,
                                                     const float* __restrict__ v,
                                                     const int* __restrict__ buckets,
                                                     const int* __restrict__ amask,
                                                     const int* __restrict__ order,
                                                     float* __restrict__ sqk,
                                                     float* __restrict__ skey,
                                                     float* __restrict__ sv,
                                                     int* __restrict__ sb,
                                                     int* __restrict__ sm) {
    int wid = threadIdx.x >> 6, lane = threadIdx.x & 63;
    int i = blockIdx.x * 4 + wid;         // flat (b*H+h)*S + is
    int b  = i / (kH * kS);
    int h  = (i / kS) % kH;
    int j  = order[i];
    size_t src = ((size_t)(b * kS + j)) * kD + h * kDH + lane;
    float qv = qk[src];
    float vv = v[src];
    float ss = qv * qv;
    for (int m = 32; m >= 1; m >>= 1) ss += __shfl_xor(ss, m, 64);
    float nrm = sqrtf(ss) + 1e-6f;
    size_t o = (size_t)i * kDH + lane;
    sqk[o]  = qv;
    skey[o] = qv / nrm;
    sv[o]   = vv;
    if (lane == 0) {
        sb[i] = buckets[(size_t)(b * kH + h) * kS + j];
        sm[i] = amask[b * kS + j];
    }
}

// ============================================================
// Chunked LSH attention with 1-chunk lookback (wrapping).
// ============================================================
__global__ __launch_bounds__(256) void attn_kernel(const float* __restrict__ sqk,
                                                   const float* __restrict__ skey,
                                                   const float* __restrict__ sv,
                                                   const int* __restrict__ sb,
                                                   const int* __restrict__ sm,
                                                   const int* __restrict__ order,
                                                   float* __restrict__ aout) {
    __shared__ float ke[2 * kC][kDH + 1];
    __shared__ float qc[kC][kDH];
    __shared__ int bc[kC], icc[kC], be[2 * kC], me[2 * kC], ie[2 * kC];
    int idx = blockIdx.x;
    int b = idx / (kH * kNC);
    int h = (idx / kNC) % kH;
    int n = idx % kNC;
    int prev = (n + kNC - 1) % kNC;
    size_t bhrow = (size_t)(b * kH + h) * kS;
    size_t kbase = bhrow * kDH;
    int tid = threadIdx.x;
    for (int t = tid; t < 2 * kC * kDH; t += 256) {
        int k = t >> 6, d = t & 63;
        int chunk = (k < kC) ? prev : n;
        int krow  = (k < kC) ? k : k - kC;
        ke[k][d] = skey[kbase + ((size_t)(chunk * kC + krow)) * kDH + d];
    }
    for (int t = tid; t < kC * kDH; t += 256) {
        int c = t >> 6, d = t & 63;
        qc[c][d] = sqk[kbase + ((size_t)(n * kC + c)) * kDH + d];
    }
    if (tid < kC) {
        bc[tid]  = sb[bhrow + n * kC + tid];
        icc[tid] = order[bhrow + n * kC + tid];
    }
    for (int t = tid; t < 2 * kC; t += 256) {
        int chunk = (t < kC) ? prev : n;
        int krow  = (t < kC) ? t : t - kC;
        be[t] = sb[bhrow + chunk * kC + krow];
        me[t] = sm[bhrow + chunk * kC + krow];
        ie[t] = order[bhrow + chunk * kC + krow];
    }
    __syncthreads();
    int wid = tid >> 6, lane = tid & 63;
    const float* vprev = sv + kbase + (size_t)prev * kC * kDH;
    const float* vcur  = sv + kbase + (size_t)n * kC * kDH;
    for (int it = 0; it < kC / 4; ++it) {
        int c = it * 4 + wid;
        int col0 = lane, col1 = kC + lane;
        float d0 = 0.f, d1 = 0.f;
#pragma unroll 8
        for (int d = 0; d < kDH; ++d) {
            float q = qc[c][d];
            d0 += q * ke[col0][d];
            d1 += q * ke[col1][d];
        }
        float v0 = d0 * 0.125f, v1 = d1 * 0.125f;   // / sqrt(64)
        int bcc = bc[c], icv = icc[c];
        if (bcc != be[col0] || me[col0] <= 0) v0 = -1e9f;
        if (bcc != be[col1] || me[col1] <= 0) v1 = -1e9f;
        if (icv == ie[col0]) v0 = -1e5f;            // self-mask last (overrides)
        if (icv == ie[col1]) v1 = -1e5f;
        float mx = fmaxf(v0, v1);
        for (int m = 32; m >= 1; m >>= 1) mx = fmaxf(mx, __shfl_xor(mx, m, 64));
        float e0 = expf(v0 - mx), e1 = expf(v1 - mx);
        float sum = e0 + e1;
        for (int m = 32; m >= 1; m >>= 1) sum += __shfl_xor(sum, m, 64);
        float p0 = e0 / sum, p1 = e1 / sum;
        float acc = 0.f;
        for (int k = 0; k < kC; ++k) {
            float a = __shfl(p0, k, 64);            // broadcast -> uniform branch
            if (a != 0.f) acc += a * vprev[(size_t)k * kDH + lane];
        }
        for (int k = 0; k < kC; ++k) {
            float a = __shfl(p1, k, 64);
            if (a != 0.f) acc += a * vcur[(size_t)k * kDH + lane];
        }
        aout[((size_t)(b * kS + icv)) * kD + h * kDH + lane] = acc;  // scatter = unsort
    }
}

// ============================================================
// host launcher
// ============================================================
extern "C" void kernel_launch(void* const* d_in, const int* in_sizes, int n_in,
                              void* d_out, int out_size, void* d_ws, size_t ws_size,
                              hipStream_t stream) {
    const int*   ids   = (const int*)d_in[0];
    const int*   amask = (const int*)d_in[1];
    const float* emb   = (const float*)d_in[2];
    const float* pos   = (const float*)d_in[3];
    const float* rot   = (const float*)d_in[4];
    const float* Wqk   = (const float*)d_in[5];
    const float* Wv    = (const float*)d_in[6];
    const float* Wo    = (const float*)d_in[7];
    const float* ln1g  = (const float*)d_in[8];
    const float* ln1b  = (const float*)d_in[9];
    const float* ln2g  = (const float*)d_in[10];
    const float* ln2b  = (const float*)d_in[11];
    const float* W1    = (const float*)d_in[12];
    const float* b1    = (const float*)d_in[13];
    const float* W2    = (const float*)d_in[14];
    const float* b2    = (const float*)d_in[15];
    const float* lnfg  = (const float*)d_in[16];
    const float* lnfb  = (const float*)d_in[17];
    const float* Wlm   = (const float*)d_in[18];
    const float* blm   = (const float*)d_in[19];
    float* out = (float*)d_out;

    const size_t NX  = (size_t)kB * kS * kD;    // 3,145,728 floats
    const size_t NBH = (size_t)kB * kH * kS;    // 49,152
    const size_t NOUT = (size_t)kB * kS * kV;   // 67,108,864 floats (full out)

    // Large fp32 scratch lives in d_out. Layout (floats):
    //   [0,NX)      x          [NX,2NX)  qk        [2NX,3NX) v
    //   [3NX,4NX)   sqk        [4NX,5NX) skey      [5NX,6NX) sv
    //   [6NX,7NX)   aoutb      [7NX,11NX) h1 (B,S,F)
    //   [NOUT-NX, NOUT): xnH/xnL bf16 split of xn (= out rows 3904..4095;
    //   the fast LM-head writes only rows < 3840; rows 3840..4095 are done
    //   AFTERWARDS by the on-the-fly fallback kernel -> no read/write race).
    float* x     = out;            // [B,S,D]
    float* qk    = out + 1 * NX;
    float* v     = out + 2 * NX;
    float* sqk   = out + 3 * NX;
    float* skey  = out + 4 * NX;
    float* sv    = out + 5 * NX;
    float* aoutb = out + 6 * NX;
    float* h1    = out + 7 * NX;   // [B,S,F] = 4*NX
    unsigned short* xnH = (unsigned short*)(out + NOUT - NX);
    unsigned short* xnL = xnH + NX;          // NX bf16 each = NX floats total
    float* xn    = (float*)d_ws;   // layernorm output [B,S,D]
    int* ibase   = (int*)((float*)d_ws + NX);
    int* buckets = ibase;
    int* order   = ibase + NBH;
    int* sb      = ibase + 2 * NBH;
    int* smv     = ibase + 3 * NBH;

    const int rows = kB * kS;  // 4096

    embed_kernel<<<rows, 256, 0, stream>>>(ids, emb, pos, x);

    for (int l = 0; l < kL; ++l) {
        ln_kernel<<<rows, 256, 0, stream>>>(x, ln1g + l * kD, ln1b + l * kD, xn);
        // Wqk always fp32: feeds bucket argmax (precision-critical)
        gemm_kernel<<<dim3(kD / 64, rows / 64), 256, 0, stream>>>(
            xn, Wqk + (size_t)l * kD * kD, nullptr, nullptr, qk, rows, kD, kD, 0);
        if (l == kL - 1) {
            // post-last-bucketing value path: bf16x3 MFMA is bucket-safe
            gemm_mfma3_kernel<<<dim3(kD / 128, rows / 128), 256, 0, stream>>>(
                xn, Wv + (size_t)l * kD * kD, nullptr, nullptr, v, rows, kD, kD, 0, 0);
        } else {
            gemm_kernel<<<dim3(kD / 64, rows / 64), 256, 0, stream>>>(
                xn, Wv + (size_t)l * kD * kD, nullptr, nullptr, v, rows, kD, kD, 0);
        }
        bucket_kernel<<<(kB * kH * kS) / 256, 256, 0, stream>>>(
            qk, rot + (size_t)l * kH * kDH * kNR, buckets);
        sort_kernel<<<kB * kH, 256, 0, stream>>>(buckets, order);
        gather_kernel<<<(kB * kH * kS) / 4, 256, 0, stream>>>(
            qk, v, buckets, amask, order, sqk, skey, sv, sb, smv);
        attn_kernel<<<kB * kH * kNC, 256, 0, stream>>>(
            sqk, skey, sv, sb, smv, order, aoutb);
        if (l == kL - 1) {
            gemm_mfma3_kernel<<<dim3(kD / 128, rows / 128), 256, 0, stream>>>(
                aoutb, Wo + (size_t)l * kD * kD, nullptr, x, x, rows, kD, kD, 0, 0);
            ln_kernel<<<rows, 256, 0, stream>>>(x, ln2g + l * kD, ln2b + l * kD, xn);
            gemm_mfma3_kernel<<<dim3(kF / 128, rows / 128), 256, 0, stream>>>(
                xn, W1 + (size_t)l * kD * kF, b1 + (size_t)l * kF, nullptr, h1, rows, kF, kD, 1, 0);
            gemm_mfma3_kernel<<<dim3(kD / 128, rows / 128), 256, 0, stream>>>(
                h1, W2 + (size_t)l * kF * kD, b2 + (size_t)l * kD, x, x, rows, kD, kF, 0, 0);
        } else {
            gemm_kernel<<<dim3(kD / 64, rows / 64), 256, 0, stream>>>(
                aoutb, Wo + (size_t)l * kD * kD, nullptr, x, x, rows, kD, kD, 0);
            ln_kernel<<<rows, 256, 0, stream>>>(x, ln2g + l * kD, ln2b + l * kD, xn);
            gemm_kernel<<<dim3(kF / 64, rows / 64), 256, 0, stream>>>(
                xn, W1 + (size_t)l * kD * kF, b1 + (size_t)l * kF, nullptr, h1, rows, kF, kD, 1);
            gemm_kernel<<<dim3(kD / 64, rows / 64), 256, 0, stream>>>(
                h1, W2 + (size_t)l * kF * kD, b2 + (size_t)l * kD, x, x, rows, kD, kF, 0);
        }
    }

    ln_kernel<<<rows, 256, 0, stream>>>(x, lnfg, lnfb, xn);
    // Split xn into bf16 hi/lo once (kills A-side conversion redundancy x128)
    convsplit_kernel<<<(int)(NX / 4 / 256), 256, 0, stream>>>(xn, xnH, xnL, (int)(NX / 4));
    // Fast LM head for rows 0..3839 (does not touch the xnH/xnL storage rows)
    lmhead_kernel<<<dim3(kV / 128, 3840 / 256), 512, 0, stream>>>(xnH, xnL, Wlm, blm, out);
    // Remaining rows 3840..4095 via on-the-fly kernel (runs after fast kernel
    // completes -> safe to overwrite the bf16 staging region)
    gemm_mfma3_kernel<<<dim3(kV / 128, 2), 256, 0, stream>>>(
        xn, Wlm, blm, nullptr, out, rows, kV, kD, 0, 3840);
}

// Round 4
// 3142.879 us; speedup vs baseline: 1.4531x; 1.0193x over previous
//
#include <hip/hip_runtime.h>
#include <math.h>

// ---- problem constants ----
constexpr int kV  = 16384;
constexpr int kD  = 768;
constexpr int kH  = 12;
constexpr int kDH = 64;
constexpr int kL  = 2;
constexpr int kF  = 3072;
constexpr int kC  = 64;     // chunk length
constexpr int kNR = 32;     // NB/2 rotations
constexpr int kNB = 64;     // number of buckets
constexpr int kB  = 2;
constexpr int kS  = 2048;
constexpr int kNC = kS / kC;  // 32 chunks

typedef __attribute__((ext_vector_type(8))) short bf16x8;
typedef __attribute__((ext_vector_type(4))) float f32x4;
typedef __attribute__((ext_vector_type(4))) unsigned short us4;
typedef __attribute__((ext_vector_type(8))) unsigned short us8;

__device__ __forceinline__ unsigned short f2bf(float f) {
    unsigned u = __float_as_uint(f);
    u += 0x7fffu + ((u >> 16) & 1u);      // round-to-nearest-even
    return (unsigned short)(u >> 16);
}
__device__ __forceinline__ float bf2f(unsigned short h) {
    return __uint_as_float(((unsigned)h) << 16);
}

#define GLOAD_LDS16(gp, lp) __builtin_amdgcn_global_load_lds( \
    (const __attribute__((address_space(1))) unsigned int*)(gp), \
    (__attribute__((address_space(3))) unsigned int*)(lp), 16, 0, 0)

// ============================================================
// x = emb[ids] + pos_emb
// ============================================================
__global__ void embed_kernel(const int* __restrict__ ids, const float* __restrict__ emb,
                             const float* __restrict__ pos, float* __restrict__ x) {
    int row = blockIdx.x;            // b*S + s
    int s = row % kS;
    int id = ids[row];
    for (int d = threadIdx.x; d < kD; d += blockDim.x)
        x[(size_t)row * kD + d] = emb[(size_t)id * kD + d] + pos[(size_t)s * kD + d];
}

// ============================================================
// LayerNorm: y = (x-m)/sqrt(var+1e-12)*g + b   (row = 768)
// ============================================================
__global__ __launch_bounds__(256) void ln_kernel(const float* __restrict__ X,
                                                 const float* __restrict__ g,
                                                 const float* __restrict__ b,
                                                 float* __restrict__ Y) {
    int row = blockIdx.x;
    size_t base = (size_t)row * kD;
    int tid = threadIdx.x;
    float vals[3];
    float s = 0.f, s2 = 0.f;
    int i = 0;
    for (int d = tid; d < kD; d += 256, ++i) {
        float v = X[base + d];
        vals[i] = v; s += v; s2 += v * v;
    }
    for (int m = 32; m >= 1; m >>= 1) {
        s  += __shfl_xor(s,  m, 64);
        s2 += __shfl_xor(s2, m, 64);
    }
    __shared__ float red[2][4];
    int wid = tid >> 6, lane = tid & 63;
    if (lane == 0) { red[0][wid] = s; red[1][wid] = s2; }
    __syncthreads();
    float ts  = red[0][0] + red[0][1] + red[0][2] + red[0][3];
    float ts2 = red[1][0] + red[1][1] + red[1][2] + red[1][3];
    float mean = ts / kD;
    float var  = ts2 / kD - mean * mean;
    float rstd = 1.0f / sqrtf(var + 1e-12f);
    i = 0;
    for (int d = tid; d < kD; d += 256, ++i)
        Y[base + d] = (vals[i] - mean) * rstd * g[d] + b[d];
}

// ============================================================
// fp32 -> bf16 hi/lo split (elementwise, float4 per thread)
// ============================================================
__global__ __launch_bounds__(256) void convsplit_kernel(const float* __restrict__ X,
                                                        unsigned short* __restrict__ H,
                                                        unsigned short* __restrict__ L,
                                                        int n4) {
    int i = blockIdx.x * 256 + threadIdx.x;
    if (i >= n4) return;
    float4 f4 = ((const float4*)X)[i];
    float f[4] = {f4.x, f4.y, f4.z, f4.w};
    us4 h4, l4;
#pragma unroll
    for (int c = 0; c < 4; ++c) {
        unsigned short h = f2bf(f[c]);
        h4[c] = h;
        l4[c] = f2bf(f[c] - bf2f(h));
    }
    ((us4*)H)[i] = h4;
    ((us4*)L)[i] = l4;
}

// ============================================================
// Generic SGEMM: C[M,N] = A[M,K] @ B[K,N] (+bias) (gelu?) (+residual)
// 64x64 tile / block(256), 4x4 micro-tile, K-step 16
// ============================================================
__global__ __launch_bounds__(256) void gemm_kernel(const float* __restrict__ A,
                                                   const float* __restrict__ Bm,
                                                   const float* __restrict__ bias,
                                                   const float* __restrict__ R,
                                                   float* __restrict__ Cm,
                                                   int M, int N, int K, int dogelu) {
    __shared__ float As[16][68];   // [kk][m], padded row -> 16B aligned
    __shared__ float Bs[16][68];   // [kk][n]
    int tid = threadIdx.x;
    int tx = tid & 15, ty = tid >> 4;
    int m0 = blockIdx.y << 6, n0 = blockIdx.x << 6;
    float acc[4][4] = {{0.f}};
    int aM = tid >> 2;             // (tid*4)/16
    int aK = (tid & 3) << 2;       // (tid*4)%16
    int bK = tid >> 4;             // (tid*4)/64
    int bN = (tid & 15) << 2;      // (tid*4)%64
    for (int k0 = 0; k0 < K; k0 += 16) {
        float4 a4 = *(const float4*)(A + (size_t)(m0 + aM) * K + k0 + aK);
        As[aK + 0][aM] = a4.x; As[aK + 1][aM] = a4.y;
        As[aK + 2][aM] = a4.z; As[aK + 3][aM] = a4.w;
        float4 b4 = *(const float4*)(Bm + (size_t)(k0 + bK) * N + n0 + bN);
        Bs[bK][bN + 0] = b4.x; Bs[bK][bN + 1] = b4.y;
        Bs[bK][bN + 2] = b4.z; Bs[bK][bN + 3] = b4.w;
        __syncthreads();
#pragma unroll
        for (int kk = 0; kk < 16; ++kk) {
            float a[4], bb[4];
#pragma unroll
            for (int i = 0; i < 4; ++i) a[i] = As[kk][ty * 4 + i];
#pragma unroll
            for (int j = 0; j < 4; ++j) bb[j] = Bs[kk][tx * 4 + j];
#pragma unroll
            for (int i = 0; i < 4; ++i)
#pragma unroll
                for (int j = 0; j < 4; ++j)
                    acc[i][j] += a[i] * bb[j];
        }
        __syncthreads();
    }
#pragma unroll
    for (int i = 0; i < 4; ++i) {
        int m = m0 + ty * 4 + i;
#pragma unroll
        for (int j = 0; j < 4; ++j) {
            int n = n0 + tx * 4 + j;
            float vv = acc[i][j];
            if (bias) vv += bias[n];
            if (dogelu) {
                float u = 0.7978845608028654f * (vv + 0.044715f * vv * vv * vv);
                vv = 0.5f * vv * (1.f + tanhf(u));
            }
            if (R) vv += R[(size_t)m * N + n];
            Cm[(size_t)m * N + n] = vv;
        }
    }
}

// ============================================================
// fp32 SGEMM, 128x128 tile / block(256), 8x8 micro-tile (2x2
// quadrants of 4x4), K-step 8. Per-element K-accumulation is
// strictly sequential with the same `acc += a*b` form as
// gemm_kernel -> bit-identical outputs (bucket-safe).
// Requires M%128==0, N%128==0, K%8==0.
// ============================================================
__global__ __launch_bounds__(256) void gemm128_kernel(const float* __restrict__ A,
                                                      const float* __restrict__ Bm,
                                                      const float* __restrict__ bias,
                                                      const float* __restrict__ R,
                                                      float* __restrict__ Cm,
                                                      int M, int N, int K, int dogelu) {
    __shared__ float As[8][132];   // [kk][m]
    __shared__ float Bs[8][132];   // [kk][n]
    int tid = threadIdx.x;
    int tx = tid & 15, ty = tid >> 4;       // 16x16 thread grid
    int m0 = blockIdx.y << 7, n0 = blockIdx.x << 7;
    float acc[8][8] = {{0.f}};
    int aR = tid >> 1;             // 0..127  (A row)
    int aC = (tid & 1) << 2;       // 0 or 4  (A k-offset)
    int bK = tid >> 5;             // 0..7    (B k row)
    int bN = (tid & 31) << 2;      // 0..124  (B col offset)
    for (int k0 = 0; k0 < K; k0 += 8) {
        float4 a4 = *(const float4*)(A + (size_t)(m0 + aR) * K + k0 + aC);
        As[aC + 0][aR] = a4.x; As[aC + 1][aR] = a4.y;
        As[aC + 2][aR] = a4.z; As[aC + 3][aR] = a4.w;
        float4 b4 = *(const float4*)(Bm + (size_t)(k0 + bK) * N + n0 + bN);
        *(float4*)(&Bs[bK][bN]) = b4;
        __syncthreads();
#pragma unroll
        for (int kk = 0; kk < 8; ++kk) {
            float a[8], bb[8];
#pragma unroll
            for (int i = 0; i < 4; ++i) {
                a[i]     = As[kk][ty * 4 + i];
                a[4 + i] = As[kk][64 + ty * 4 + i];
                bb[i]    = Bs[kk][tx * 4 + i];
                bb[4 + i] = Bs[kk][64 + tx * 4 + i];
            }
#pragma unroll
            for (int i = 0; i < 8; ++i)
#pragma unroll
                for (int j = 0; j < 8; ++j)
                    acc[i][j] += a[i] * bb[j];
        }
        __syncthreads();
    }
#pragma unroll
    for (int i = 0; i < 8; ++i) {
        int m = m0 + ((i >> 2) << 6) + ty * 4 + (i & 3);
#pragma unroll
        for (int j = 0; j < 8; ++j) {
            int n = n0 + ((j >> 2) << 6) + tx * 4 + (j & 3);
            float vv = acc[i][j];
            if (bias) vv += bias[n];
            if (dogelu) {
                float u = 0.7978845608028654f * (vv + 0.044715f * vv * vv * vv);
                vv = 0.5f * vv * (1.f + tanhf(u));
            }
            if (R) vv += R[(size_t)m * N + n];
            Cm[(size_t)m * N + n] = vv;
        }
    }
}

// ============================================================
// bf16x3 split-precision MFMA GEMM (on-the-fly conversion):
// C = A @ B (+bias) (gelu?) (+residual), fp32 in/out.
// 128x128 tile, BK=32, 4 waves (2x2), mfma_f32_16x16x32_bf16.
// Requires M%128==0 (from mbase), N%128==0, K%32==0.
// ============================================================
__global__ __launch_bounds__(256) void gemm_mfma3_kernel(const float* __restrict__ A,
                                                         const float* __restrict__ Bm,
                                                         const float* __restrict__ bias,
                                                         const float* __restrict__ R,
                                                         float* __restrict__ Cm,
                                                         int M, int N, int K,
                                                         int dogelu, int mbase) {
    __shared__ unsigned short Ah[128][40], Al[128][40];   // [m][k], k contiguous
    __shared__ unsigned short Bh[128][40], Bl[128][40];   // [n][k], k contiguous
    int tid = threadIdx.x;
    int m0 = mbase + (blockIdx.y << 7), n0 = blockIdx.x << 7;
    int lane = tid & 63, wid = tid >> 6;
    int wm = wid >> 1, wn = wid & 1;      // 2x2 wave grid, wave tile 64x64
    int lr = lane & 15, lg = lane >> 4;   // fragment row/col & k-group

    f32x4 acc[4][4] = {};

    int aRow = tid >> 3;               // 0..31 (x4 passes -> 128 rows)
    int aK4  = (tid & 7) << 2;         // k offset 0..28 step 4
    int bN   = tid & 127;              // 0..127
    int bK0  = (tid >> 7) << 4;        // 0 or 16

    for (int k0 = 0; k0 < K; k0 += 32) {
#pragma unroll
        for (int rp = 0; rp < 4; ++rp) {
            int row = aRow + rp * 32;
            float4 a4 = *(const float4*)(A + (size_t)(m0 + row) * K + k0 + aK4);
            float f[4] = {a4.x, a4.y, a4.z, a4.w};
            us4 h4, l4;
#pragma unroll
            for (int c = 0; c < 4; ++c) {
                unsigned short h = f2bf(f[c]);
                h4[c] = h;
                l4[c] = f2bf(f[c] - bf2f(h));
            }
            *(us4*)(&Ah[row][aK4]) = h4;
            *(us4*)(&Al[row][aK4]) = l4;
        }
        {
            unsigned short hb[16], lb[16];
#pragma unroll
            for (int j = 0; j < 16; ++j) {
                float f = Bm[(size_t)(k0 + bK0 + j) * N + n0 + bN];
                unsigned short h = f2bf(f);
                hb[j] = h;
                lb[j] = f2bf(f - bf2f(h));
            }
#pragma unroll
            for (int q = 0; q < 4; ++q) {
                us4 h4, l4;
#pragma unroll
                for (int c = 0; c < 4; ++c) { h4[c] = hb[q * 4 + c]; l4[c] = lb[q * 4 + c]; }
                *(us4*)(&Bh[bN][bK0 + q * 4]) = h4;
                *(us4*)(&Bl[bN][bK0 + q * 4]) = l4;
            }
        }
        __syncthreads();
        bf16x8 fah[4], fal[4], fbh[4], fbl[4];
#pragma unroll
        for (int i = 0; i < 4; ++i) {
            fah[i] = *(const bf16x8*)(&Ah[wm * 64 + i * 16 + lr][lg * 8]);
            fal[i] = *(const bf16x8*)(&Al[wm * 64 + i * 16 + lr][lg * 8]);
            fbh[i] = *(const bf16x8*)(&Bh[wn * 64 + i * 16 + lr][lg * 8]);
            fbl[i] = *(const bf16x8*)(&Bl[wn * 64 + i * 16 + lr][lg * 8]);
        }
#pragma unroll
        for (int i = 0; i < 4; ++i)
#pragma unroll
            for (int j = 0; j < 4; ++j) {
                acc[i][j] = __builtin_amdgcn_mfma_f32_16x16x32_bf16(fah[i], fbh[j], acc[i][j], 0, 0, 0);
                acc[i][j] = __builtin_amdgcn_mfma_f32_16x16x32_bf16(fah[i], fbl[j], acc[i][j], 0, 0, 0);
                acc[i][j] = __builtin_amdgcn_mfma_f32_16x16x32_bf16(fal[i], fbh[j], acc[i][j], 0, 0, 0);
            }
        __syncthreads();
    }
#pragma unroll
    for (int j = 0; j < 4; ++j) {
        int col = n0 + wn * 64 + j * 16 + lr;
        float bv = bias ? bias[col] : 0.f;
#pragma unroll
        for (int i = 0; i < 4; ++i) {
            int rowb = m0 + wm * 64 + i * 16 + lg * 4;
#pragma unroll
            for (int r = 0; r < 4; ++r) {
                float vv = acc[i][j][r] + bv;
                if (dogelu) {
                    float u = 0.7978845608028654f * (vv + 0.044715f * vv * vv * vv);
                    vv = 0.5f * vv * (1.f + tanhf(u));
                }
                if (R) vv += R[(size_t)(rowb + r) * N + col];
                Cm[(size_t)(rowb + r) * N + col] = vv;
            }
        }
    }
}

// ============================================================
// LM-head fast GEMM: C[0..3839, 16384] = xn @ Wlm + blm, bf16x3.
// A precomputed as bf16 hi/lo (xnH/xnL). 256x128 tile, BK=32,
// 512 threads (8 waves, 4x2 grid, 64x64 wave tiles).
// ============================================================
__global__ __launch_bounds__(512) void lmhead_kernel(const unsigned short* __restrict__ AHg,
                                                     const unsigned short* __restrict__ ALg,
                                                     const float* __restrict__ Wlm,
                                                     const float* __restrict__ blm,
                                                     float* __restrict__ Cm) {
    __shared__ unsigned short AH[256 * 32], AL[256 * 32];
    __shared__ unsigned short BH[128 * 32], BL[128 * 32];
    int tid = threadIdx.x;
    int lane = tid & 63, wid = tid >> 6;
    int wm = wid >> 1, wn = wid & 1;       // 4x2 wave grid
    int lr = lane & 15, lg = lane >> 4;
    int m0 = blockIdx.y << 8;              // 256-row tiles (rows < 3840)
    int n0 = blockIdx.x << 7;

    f32x4 acc[4][4] = {};

    int arow_in = lane >> 2;
    int aphys   = lane & 3;
    int o0 = wid * 2, o1 = wid * 2 + 1;
    int row0 = o0 * 16 + arow_in;
    int row1 = o1 * 16 + arow_in;
    int s0 = aphys ^ ((row0 >> 1) & 3);
    int s1 = aphys ^ ((row1 >> 1) & 3);
    size_t ga0 = (size_t)(m0 + row0) * 768 + s0 * 8;
    size_t ga1 = (size_t)(m0 + row1) * 768 + s1 * 8;

    int bcol = tid & 127;
    int bsl  = tid >> 7;                   // logical k-slot (8 k's each)
    int bphys = bsl ^ ((bcol >> 1) & 3);
    const size_t bstr = 16384;

    for (int k0 = 0; k0 < 768; k0 += 32) {
        GLOAD_LDS16(AHg + ga0 + k0, &AH[o0 * 512]);
        GLOAD_LDS16(AHg + ga1 + k0, &AH[o1 * 512]);
        GLOAD_LDS16(ALg + ga0 + k0, &AL[o0 * 512]);
        GLOAD_LDS16(ALg + ga1 + k0, &AL[o1 * 512]);
        const float* bp = Wlm + (size_t)(k0 + bsl * 8) * bstr + n0 + bcol;
        float f[8];
#pragma unroll
        for (int j = 0; j < 8; ++j) f[j] = bp[(size_t)j * bstr];
        us8 hv, lv;
#pragma unroll
        for (int j = 0; j < 8; ++j) {
            unsigned short h = f2bf(f[j]);
            hv[j] = h;
            lv[j] = f2bf(f[j] - bf2f(h));
        }
        *(us8*)(&BH[bcol * 32 + bphys * 8]) = hv;
        *(us8*)(&BL[bcol * 32 + bphys * 8]) = lv;
        __syncthreads();
        bf16x8 fah[4], fal[4];
#pragma unroll
        for (int i = 0; i < 4; ++i) {
            int ar = wm * 64 + i * 16 + lr;
            int sa = (lg ^ ((ar >> 1) & 3)) * 8;
            fah[i] = *(const bf16x8*)(&AH[ar * 32 + sa]);
            fal[i] = *(const bf16x8*)(&AL[ar * 32 + sa]);
        }
#pragma unroll
        for (int j = 0; j < 4; ++j) {
            int bc = wn * 64 + j * 16 + lr;
            int sb = (lg ^ ((bc >> 1) & 3)) * 8;
            bf16x8 fbh = *(const bf16x8*)(&BH[bc * 32 + sb]);
            bf16x8 fbl = *(const bf16x8*)(&BL[bc * 32 + sb]);
#pragma unroll
            for (int i = 0; i < 4; ++i) {
                acc[i][j] = __builtin_amdgcn_mfma_f32_16x16x32_bf16(fah[i], fbh, acc[i][j], 0, 0, 0);
                acc[i][j] = __builtin_amdgcn_mfma_f32_16x16x32_bf16(fah[i], fbl, acc[i][j], 0, 0, 0);
                acc[i][j] = __builtin_amdgcn_mfma_f32_16x16x32_bf16(fal[i], fbh, acc[i][j], 0, 0, 0);
            }
        }
        __syncthreads();
    }
#pragma unroll
    for (int j = 0; j < 4; ++j) {
        int col = n0 + wn * 64 + j * 16 + lr;
        float bv = blm[col];
#pragma unroll
        for (int i = 0; i < 4; ++i) {
            int rowb = m0 + wm * 64 + i * 16 + lg * 4;
#pragma unroll
            for (int r = 0; r < 4; ++r)
                Cm[(size_t)(rowb + r) * 16384 + col] = acc[i][j][r] + bv;
        }
    }
}

// ============================================================
// LSH bucketing: rotated = qk . rot ; bucket = argmax([r,-r])
// ============================================================
__global__ void bucket_kernel(const float* __restrict__ qk, const float* __restrict__ rot,
                              int* __restrict__ buckets) {
    int t = blockIdx.x * 256 + threadIdx.x;
    if (t >= kB * kH * kS) return;
    int b = t / (kH * kS);
    int h = (t / kS) % kH;
    int s = t % kS;
    const float* q  = qk + ((size_t)(b * kS + s)) * kD + h * kDH;
    const float* rr = rot + (size_t)h * kDH * kNR;
    float rv[kNR];
    for (int r = 0; r < kNR; ++r) {
        double acc = 0.0;
        for (int d = 0; d < kDH; ++d)
            acc += (double)q[d] * (double)rr[d * kNR + r];
        rv[r] = (float)acc;
    }
    float best = -INFINITY; int bi = 0;
    for (int idx = 0; idx < 2 * kNR; ++idx) {
        float v = (idx < kNR) ? rv[idx] : -rv[idx - kNR];
        if (v > best) { best = v; bi = idx; }   // first occurrence of max
    }
    buckets[t] = bi;
}

// ============================================================
// Stable counting sort of positions by bucket, per (b,h)
// ============================================================
__global__ __launch_bounds__(256) void sort_kernel(const int* __restrict__ buckets,
                                                   int* __restrict__ order) {
    __shared__ int sb[kS];
    __shared__ int hist[kNB];
    __shared__ int offs[kNB];
    int bh = blockIdx.x;
    const int* bk = buckets + (size_t)bh * kS;
    for (int s = threadIdx.x; s < kS; s += 256) sb[s] = bk[s];
    for (int i = threadIdx.x; i < kNB; i += 256) hist[i] = 0;
    __syncthreads();
    for (int s = threadIdx.x; s < kS; s += 256) atomicAdd(&hist[sb[s]], 1);
    __syncthreads();
    if (threadIdx.x == 0) {
        int run = 0;
        for (int k = 0; k < kNB; ++k) { offs[k] = run; run += hist[k]; }
    }
    __syncthreads();
    for (int s = threadIdx.x; s < kS; s += 256) {
        int bkt = sb[s];
        int cnt = 0;
        for (int t = 0; t < s; ++t) cnt += (sb[t] == bkt) ? 1 : 0;
        order[(size_t)bh * kS + offs[bkt] + cnt] = s;
    }
}

// ============================================================
// Gather sorted qk/v, L2-normalize keys, gather buckets & mask.
// ============================================================
__global__ __launch_bounds__(256) void gather_kernel(const float* __restrict__ qk,
                                                     const float* __restrict__ v,
                                                     const int* __restrict__ buckets,
                                                     const int* __restrict__ amask,
                                                     const int* __restrict__ order,
                                                     float* __restrict__ sqk,
                                                     float* __restrict__ skey,
                                                     float* __restrict__ sv,
                                                     int* __restrict__ sb,
                                                     int* __restrict__ sm) {
    int wid = threadIdx.x >> 6, lane = threadIdx.x & 63;
    int i = blockIdx.x * 4 + wid;         // flat (b*H+h)*S + is
    int b  = i / (kH * kS);
    int h  = (i / kS) % kH;
    int j  = order[i];
    size_t src = ((size_t)(b * kS + j)) * kD + h * kDH + lane;
    float qv = qk[src];
    float vv = v[src];
    float ss = qv * qv;
    for (int m = 32; m >= 1; m >>= 1) ss += __shfl_xor(ss, m, 64);
    float nrm = sqrtf(ss) + 1e-6f;
    size_t o = (size_t)i * kDH + lane;
    sqk[o]  = qv;
    skey[o] = qv / nrm;
    sv[o]   = vv;
    if (lane == 0) {
        sb[i] = buckets[(size_t)(b * kH + h) * kS + j];
        sm[i] = amask[b * kS + j];
    }
}

// ============================================================
// Chunked LSH attention with 1-chunk lookback (wrapping).
// PV: loads are hoisted unconditionally in groups of 8 (pipelined);
// the conditional ADD structure of the verified round-2 kernel is
// kept EXACTLY (same terms, same order -> bit-identical output).
// ============================================================
__global__ __launch_bounds__(256) void attn_kernel(const float* __restrict__ sqk,
                                                   const float* __restrict__ skey,
                                                   const float* __restrict__ sv,
                                                   const int* __restrict__ sb,
                                                   const int* __restrict__ sm,
                                                   const int* __restrict__ order,
                                                   float* __restrict__ aout) {
    __shared__ float ke[2 * kC][kDH + 1];
    __shared__ float qc[kC][kDH];
    __shared__ int bc[kC], icc[kC], be[2 * kC], me[2 * kC], ie[2 * kC];
    int idx = blockIdx.x;
    int b = idx / (kH * kNC);
    int h = (idx / kNC) % kH;
    int n = idx % kNC;
    int prev = (n + kNC - 1) % kNC;
    size_t bhrow = (size_t)(b * kH + h) * kS;
    size_t kbase = bhrow * kDH;
    int tid = threadIdx.x;
    for (int t = tid; t < 2 * kC * kDH; t += 256) {
        int k = t >> 6, d = t & 63;
        int chunk = (k < kC) ? prev : n;
        int krow  = (k < kC) ? k : k - kC;
        ke[k][d] = skey[kbase + ((size_t)(chunk * kC + krow)) * kDH + d];
    }
    for (int t = tid; t < kC * kDH; t += 256) {
        int c = t >> 6, d = t & 63;
        qc[c][d] = sqk[kbase + ((size_t)(n * kC + c)) * kDH + d];
    }
    if (tid < kC) {
        bc[tid]  = sb[bhrow + n * kC + tid];
        icc[tid] = order[bhrow + n * kC + tid];
    }
    for (int t = tid; t < 2 * kC; t += 256) {
        int chunk = (t < kC) ? prev : n;
        int krow  = (t < kC) ? t : t - kC;
        be[t] = sb[bhrow + chunk * kC + krow];
        me[t] = sm[bhrow + chunk * kC + krow];
        ie[t] = order[bhrow + chunk * kC + krow];
    }
    __syncthreads();
    int wid = tid >> 6, lane = tid & 63;
    const float* vprev = sv + kbase + (size_t)prev * kC * kDH;
    const float* vcur  = sv + kbase + (size_t)n * kC * kDH;
    for (int it = 0; it < kC / 4; ++it) {
        int c = it * 4 + wid;
        int col0 = lane, col1 = kC + lane;
        float d0 = 0.f, d1 = 0.f;
#pragma unroll 8
        for (int d = 0; d < kDH; ++d) {
            float q = qc[c][d];
            d0 += q * ke[col0][d];
            d1 += q * ke[col1][d];
        }
        float v0 = d0 * 0.125f, v1 = d1 * 0.125f;   // / sqrt(64)
        int bcc = bc[c], icv = icc[c];
        if (bcc != be[col0] || me[col0] <= 0) v0 = -1e9f;
        if (bcc != be[col1] || me[col1] <= 0) v1 = -1e9f;
        if (icv == ie[col0]) v0 = -1e5f;            // self-mask last (overrides)
        if (icv == ie[col1]) v1 = -1e5f;
        float mx = fmaxf(v0, v1);
        for (int m = 32; m >= 1; m >>= 1) mx = fmaxf(mx, __shfl_xor(mx, m, 64));
        float e0 = expf(v0 - mx), e1 = expf(v1 - mx);
        float sum = e0 + e1;
        for (int m = 32; m >= 1; m >>= 1) sum += __shfl_xor(sum, m, 64);
        float p0 = e0 / sum, p1 = e1 / sum;
        float acc = 0.f;
        for (int kb = 0; kb < kC; kb += 8) {
            float aa[8], vv[8];
#pragma unroll
            for (int j = 0; j < 8; ++j) {
                aa[j] = __shfl(p0, kb + j, 64);                 // uniform broadcast
                vv[j] = vprev[(size_t)(kb + j) * kDH + lane];   // unconditional load
            }
#pragma unroll
            for (int j = 0; j < 8; ++j)
                if (aa[j] != 0.f) acc += aa[j] * vv[j];         // round-2 semantics
        }
        for (int kb = 0; kb < kC; kb += 8) {
            float aa[8], vv[8];
#pragma unroll
            for (int j = 0; j < 8; ++j) {
                aa[j] = __shfl(p1, kb + j, 64);
                vv[j] = vcur[(size_t)(kb + j) * kDH + lane];
            }
#pragma unroll
            for (int j = 0; j < 8; ++j)
                if (aa[j] != 0.f) acc += aa[j] * vv[j];
        }
        aout[((size_t)(b * kS + icv)) * kD + h * kDH + lane] = acc;  // scatter = unsort
    }
}

// ============================================================
// host launcher
// ============================================================
extern "C" void kernel_launch(void* const* d_in, const int* in_sizes, int n_in,
                              void* d_out, int out_size, void* d_ws, size_t ws_size,
                              hipStream_t stream) {
    const int*   ids   = (const int*)d_in[0];
    const int*   amask = (const int*)d_in[1];
    const float* emb   = (const float*)d_in[2];
    const float* pos   = (const float*)d_in[3];
    const float* rot   = (const float*)d_in[4];
    const float* Wqk   = (const float*)d_in[5];
    const float* Wv    = (const float*)d_in[6];
    const float* Wo    = (const float*)d_in[7];
    const float* ln1g  = (const float*)d_in[8];
    const float* ln1b  = (const float*)d_in[9];
    const float* ln2g  = (const float*)d_in[10];
    const float* ln2b  = (const float*)d_in[11];
    const float* W1    = (const float*)d_in[12];
    const float* b1    = (const float*)d_in[13];
    const float* W2    = (const float*)d_in[14];
    const float* b2    = (const float*)d_in[15];
    const float* lnfg  = (const float*)d_in[16];
    const float* lnfb  = (const float*)d_in[17];
    const float* Wlm   = (const float*)d_in[18];
    const float* blm   = (const float*)d_in[19];
    float* out = (float*)d_out;

    const size_t NX  = (size_t)kB * kS * kD;    // 3,145,728 floats
    const size_t NBH = (size_t)kB * kH * kS;    // 49,152
    const size_t NOUT = (size_t)kB * kS * kV;   // 67,108,864 floats (full out)

    // Large fp32 scratch lives in d_out. Layout (floats):
    //   [0,NX) x  [NX,2NX) qk  [2NX,3NX) v  [3NX,4NX) sqk  [4NX,5NX) skey
    //   [5NX,6NX) sv  [6NX,7NX) aoutb  [7NX,11NX) h1
    //   [NOUT-NX, NOUT): xnH/xnL bf16 split of xn (out rows 3904..4095;
    //   fast LM-head writes rows < 3840; rows 3840..4095 done afterwards
    //   by the on-the-fly fallback kernel -> no race).
    float* x     = out;            // [B,S,D]
    float* qk    = out + 1 * NX;
    float* v     = out + 2 * NX;
    float* sqk   = out + 3 * NX;
    float* skey  = out + 4 * NX;
    float* sv    = out + 5 * NX;
    float* aoutb = out + 6 * NX;
    float* h1    = out + 7 * NX;   // [B,S,F] = 4*NX
    unsigned short* xnH = (unsigned short*)(out + NOUT - NX);
    unsigned short* xnL = xnH + NX;          // NX bf16 each = NX floats total
    float* xn    = (float*)d_ws;   // layernorm output [B,S,D]
    int* ibase   = (int*)((float*)d_ws + NX);
    int* buckets = ibase;
    int* order   = ibase + NBH;
    int* sb      = ibase + 2 * NBH;
    int* smv     = ibase + 3 * NBH;

    const int rows = kB * kS;  // 4096

    embed_kernel<<<rows, 256, 0, stream>>>(ids, emb, pos, x);

    for (int l = 0; l < kL; ++l) {
        ln_kernel<<<rows, 256, 0, stream>>>(x, ln1g + l * kD, ln1b + l * kD, xn);
        // Wqk always fp32: feeds bucket argmax (precision-critical)
        gemm_kernel<<<dim3(kD / 64, rows / 64), 256, 0, stream>>>(
            xn, Wqk + (size_t)l * kD * kD, nullptr, nullptr, qk, rows, kD, kD, 0);
        if (l == kL - 1) {
            // post-last-bucketing value path: bf16x3 MFMA is bucket-safe
            gemm_mfma3_kernel<<<dim3(kD / 128, rows / 128), 256, 0, stream>>>(
                xn, Wv + (size_t)l * kD * kD, nullptr, nullptr, v, rows, kD, kD, 0, 0);
        } else {
            gemm_kernel<<<dim3(kD / 64, rows / 64), 256, 0, stream>>>(
                xn, Wv + (size_t)l * kD * kD, nullptr, nullptr, v, rows, kD, kD, 0);
        }
        bucket_kernel<<<(kB * kH * kS) / 256, 256, 0, stream>>>(
            qk, rot + (size_t)l * kH * kDH * kNR, buckets);
        sort_kernel<<<kB * kH, 256, 0, stream>>>(buckets, order);
        gather_kernel<<<(kB * kH * kS) / 4, 256, 0, stream>>>(
            qk, v, buckets, amask, order, sqk, skey, sv, sb, smv);
        attn_kernel<<<kB * kH * kNC, 256, 0, stream>>>(
            sqk, skey, sv, sb, smv, order, aoutb);
        if (l == kL - 1) {
            gemm_mfma3_kernel<<<dim3(kD / 128, rows / 128), 256, 0, stream>>>(
                aoutb, Wo + (size_t)l * kD * kD, nullptr, x, x, rows, kD, kD, 0, 0);
            ln_kernel<<<rows, 256, 0, stream>>>(x, ln2g + l * kD, ln2b + l * kD, xn);
            gemm_mfma3_kernel<<<dim3(kF / 128, rows / 128), 256, 0, stream>>>(
                xn, W1 + (size_t)l * kD * kF, b1 + (size_t)l * kF, nullptr, h1, rows, kF, kD, 1, 0);
            gemm_mfma3_kernel<<<dim3(kD / 128, rows / 128), 256, 0, stream>>>(
                h1, W2 + (size_t)l * kF * kD, b2 + (size_t)l * kD, x, x, rows, kD, kF, 0, 0);
        } else {
            gemm_kernel<<<dim3(kD / 64, rows / 64), 256, 0, stream>>>(
                aoutb, Wo + (size_t)l * kD * kD, nullptr, x, x, rows, kD, kD, 0);
            ln_kernel<<<rows, 256, 0, stream>>>(x, ln2g + l * kD, ln2b + l * kD, xn);
            // layer-0 FFN: fp32, bit-identical k-order, faster 128x128 tile
            gemm128_kernel<<<dim3(kF / 128, rows / 128), 256, 0, stream>>>(
                xn, W1 + (size_t)l * kD * kF, b1 + (size_t)l * kF, nullptr, h1, rows, kF, kD, 1);
            gemm128_kernel<<<dim3(kD / 128, rows / 128), 256, 0, stream>>>(
                h1, W2 + (size_t)l * kF * kD, b2 + (size_t)l * kD, x, x, rows, kD, kF, 0);
        }
    }

    ln_kernel<<<rows, 256, 0, stream>>>(x, lnfg, lnfb, xn);
    // Split xn into bf16 hi/lo once (kills A-side conversion redundancy x128)
    convsplit_kernel<<<(int)(NX / 4 / 256), 256, 0, stream>>>(xn, xnH, xnL, (int)(NX / 4));
    // Fast LM head for rows 0..3839
    lmhead_kernel<<<dim3(kV / 128, 3840 / 256), 512, 0, stream>>>(xnH, xnL, Wlm, blm, out);
    // Remaining rows 3840..4095 (runs after fast kernel -> safe to overwrite
    // the bf16 staging region)
    gemm_mfma3_kernel<<<dim3(kV / 128, 2), 256, 0, stream>>>(
        xn, Wlm, blm, nullptr, out, rows, kV, kD, 0, 3840);
}

// Round 5
// 2855.826 us; speedup vs baseline: 1.5992x; 1.1005x over previous
//
#include <hip/hip_runtime.h>
#include <math.h>

// ---- problem constants ----
constexpr int kV  = 16384;
constexpr int kD  = 768;
constexpr int kH  = 12;
constexpr int kDH = 64;
constexpr int kL  = 2;
constexpr int kF  = 3072;
constexpr int kC  = 64;     // chunk length
constexpr int kNR = 32;     // NB/2 rotations
constexpr int kNB = 64;     // number of buckets
constexpr int kB  = 2;
constexpr int kS  = 2048;
constexpr int kNC = kS / kC;  // 32 chunks

typedef __attribute__((ext_vector_type(8))) short bf16x8;
typedef __attribute__((ext_vector_type(4))) float f32x4;
typedef __attribute__((ext_vector_type(4))) unsigned short us4;
typedef __attribute__((ext_vector_type(8))) unsigned short us8;

__device__ __forceinline__ unsigned short f2bf(float f) {
    unsigned u = __float_as_uint(f);
    u += 0x7fffu + ((u >> 16) & 1u);      // round-to-nearest-even
    return (unsigned short)(u >> 16);
}
__device__ __forceinline__ float bf2f(unsigned short h) {
    return __uint_as_float(((unsigned)h) << 16);
}

#define GLOAD_LDS16(gp, lp) __builtin_amdgcn_global_load_lds( \
    (const __attribute__((address_space(1))) unsigned int*)(gp), \
    (__attribute__((address_space(3))) unsigned int*)(lp), 16, 0, 0)

// ============================================================
// x = emb[ids] + pos_emb
// ============================================================
__global__ void embed_kernel(const int* __restrict__ ids, const float* __restrict__ emb,
                             const float* __restrict__ pos, float* __restrict__ x) {
    int row = blockIdx.x;            // b*S + s
    int s = row % kS;
    int id = ids[row];
    for (int d = threadIdx.x; d < kD; d += blockDim.x)
        x[(size_t)row * kD + d] = emb[(size_t)id * kD + d] + pos[(size_t)s * kD + d];
}

// ============================================================
// LayerNorm: y = (x-m)/sqrt(var+1e-12)*g + b   (row = 768)
// ============================================================
__global__ __launch_bounds__(256) void ln_kernel(const float* __restrict__ X,
                                                 const float* __restrict__ g,
                                                 const float* __restrict__ b,
                                                 float* __restrict__ Y) {
    int row = blockIdx.x;
    size_t base = (size_t)row * kD;
    int tid = threadIdx.x;
    float vals[3];
    float s = 0.f, s2 = 0.f;
    int i = 0;
    for (int d = tid; d < kD; d += 256, ++i) {
        float v = X[base + d];
        vals[i] = v; s += v; s2 += v * v;
    }
    for (int m = 32; m >= 1; m >>= 1) {
        s  += __shfl_xor(s,  m, 64);
        s2 += __shfl_xor(s2, m, 64);
    }
    __shared__ float red[2][4];
    int wid = tid >> 6, lane = tid & 63;
    if (lane == 0) { red[0][wid] = s; red[1][wid] = s2; }
    __syncthreads();
    float ts  = red[0][0] + red[0][1] + red[0][2] + red[0][3];
    float ts2 = red[1][0] + red[1][1] + red[1][2] + red[1][3];
    float mean = ts / kD;
    float var  = ts2 / kD - mean * mean;
    float rstd = 1.0f / sqrtf(var + 1e-12f);
    i = 0;
    for (int d = tid; d < kD; d += 256, ++i)
        Y[base + d] = (vals[i] - mean) * rstd * g[d] + b[d];
}

// ============================================================
// fp32 -> bf16 hi/lo split (elementwise, float4 per thread)
// ============================================================
__global__ __launch_bounds__(256) void convsplit_kernel(const float* __restrict__ X,
                                                        unsigned short* __restrict__ H,
                                                        unsigned short* __restrict__ L,
                                                        int n4) {
    int i = blockIdx.x * 256 + threadIdx.x;
    if (i >= n4) return;
    float4 f4 = ((const float4*)X)[i];
    float f[4] = {f4.x, f4.y, f4.z, f4.w};
    us4 h4, l4;
#pragma unroll
    for (int c = 0; c < 4; ++c) {
        unsigned short h = f2bf(f[c]);
        h4[c] = h;
        l4[c] = f2bf(f[c] - bf2f(h));
    }
    ((us4*)H)[i] = h4;
    ((us4*)L)[i] = l4;
}

// ============================================================
// Generic SGEMM: C[M,N] = A[M,K] @ B[K,N] (+bias) (gelu?) (+residual)
// 64x64 tile / block(256), 4x4 micro-tile, K-step 16
// ============================================================
__global__ __launch_bounds__(256) void gemm_kernel(const float* __restrict__ A,
                                                   const float* __restrict__ Bm,
                                                   const float* __restrict__ bias,
                                                   const float* __restrict__ R,
                                                   float* __restrict__ Cm,
                                                   int M, int N, int K, int dogelu) {
    __shared__ float As[16][68];   // [kk][m], padded row -> 16B aligned
    __shared__ float Bs[16][68];   // [kk][n]
    int tid = threadIdx.x;
    int tx = tid & 15, ty = tid >> 4;
    int m0 = blockIdx.y << 6, n0 = blockIdx.x << 6;
    float acc[4][4] = {{0.f}};
    int aM = tid >> 2;             // (tid*4)/16
    int aK = (tid & 3) << 2;       // (tid*4)%16
    int bK = tid >> 4;             // (tid*4)/64
    int bN = (tid & 15) << 2;      // (tid*4)%64
    for (int k0 = 0; k0 < K; k0 += 16) {
        float4 a4 = *(const float4*)(A + (size_t)(m0 + aM) * K + k0 + aK);
        As[aK + 0][aM] = a4.x; As[aK + 1][aM] = a4.y;
        As[aK + 2][aM] = a4.z; As[aK + 3][aM] = a4.w;
        float4 b4 = *(const float4*)(Bm + (size_t)(k0 + bK) * N + n0 + bN);
        Bs[bK][bN + 0] = b4.x; Bs[bK][bN + 1] = b4.y;
        Bs[bK][bN + 2] = b4.z; Bs[bK][bN + 3] = b4.w;
        __syncthreads();
#pragma unroll
        for (int kk = 0; kk < 16; ++kk) {
            float a[4], bb[4];
#pragma unroll
            for (int i = 0; i < 4; ++i) a[i] = As[kk][ty * 4 + i];
#pragma unroll
            for (int j = 0; j < 4; ++j) bb[j] = Bs[kk][tx * 4 + j];
#pragma unroll
            for (int i = 0; i < 4; ++i)
#pragma unroll
                for (int j = 0; j < 4; ++j)
                    acc[i][j] += a[i] * bb[j];
        }
        __syncthreads();
    }
#pragma unroll
    for (int i = 0; i < 4; ++i) {
        int m = m0 + ty * 4 + i;
#pragma unroll
        for (int j = 0; j < 4; ++j) {
            int n = n0 + tx * 4 + j;
            float vv = acc[i][j];
            if (bias) vv += bias[n];
            if (dogelu) {
                float u = 0.7978845608028654f * (vv + 0.044715f * vv * vv * vv);
                vv = 0.5f * vv * (1.f + tanhf(u));
            }
            if (R) vv += R[(size_t)m * N + n];
            Cm[(size_t)m * N + n] = vv;
        }
    }
}

// ============================================================
// fp32 SGEMM v2: 128x64 tile / block(256), 8x4 micro-tile
// (32 acc regs -- fits register budget, unlike the spilled 8x8),
// K-step 16. Per-element K-accumulation strictly ascending with
// the same `acc += a*b` form as gemm_kernel -> bit-identical
// outputs (bucket-safe). Requires M%128==0, N%64==0, K%16==0.
// ============================================================
__global__ __launch_bounds__(256) void gemm_v2_kernel(const float* __restrict__ A,
                                                      const float* __restrict__ Bm,
                                                      const float* __restrict__ bias,
                                                      const float* __restrict__ R,
                                                      float* __restrict__ Cm,
                                                      int M, int N, int K, int dogelu) {
    __shared__ float As[16][132];  // [kk][m]
    __shared__ float Bs[16][68];   // [kk][n]
    int tid = threadIdx.x;
    int tx = tid & 15, ty = tid >> 4;       // 16x16 grid: ty->8 rows, tx->4 cols
    int m0 = blockIdx.y << 7, n0 = blockIdx.x << 6;
    float acc[8][4] = {{0.f}};
    int aR = tid >> 1;             // 0..127  (A row)
    int aC = (tid & 1) << 3;       // 0 or 8  (A k-offset)
    int bK = tid >> 4;             // 0..15   (B k row)
    int bN = (tid & 15) << 2;      // 0..60   (B col offset)
    for (int k0 = 0; k0 < K; k0 += 16) {
        const float* ap = A + (size_t)(m0 + aR) * K + k0 + aC;
        float4 a4 = *(const float4*)(ap);
        float4 a5 = *(const float4*)(ap + 4);
        As[aC + 0][aR] = a4.x; As[aC + 1][aR] = a4.y;
        As[aC + 2][aR] = a4.z; As[aC + 3][aR] = a4.w;
        As[aC + 4][aR] = a5.x; As[aC + 5][aR] = a5.y;
        As[aC + 6][aR] = a5.z; As[aC + 7][aR] = a5.w;
        float4 b4 = *(const float4*)(Bm + (size_t)(k0 + bK) * N + n0 + bN);
        *(float4*)(&Bs[bK][bN]) = b4;
        __syncthreads();
#pragma unroll
        for (int kk = 0; kk < 16; ++kk) {
            float a[8], bb[4];
#pragma unroll
            for (int i = 0; i < 8; ++i) a[i] = As[kk][ty * 8 + i];
#pragma unroll
            for (int j = 0; j < 4; ++j) bb[j] = Bs[kk][tx * 4 + j];
#pragma unroll
            for (int i = 0; i < 8; ++i)
#pragma unroll
                for (int j = 0; j < 4; ++j)
                    acc[i][j] += a[i] * bb[j];
        }
        __syncthreads();
    }
#pragma unroll
    for (int i = 0; i < 8; ++i) {
        int m = m0 + ty * 8 + i;
#pragma unroll
        for (int j = 0; j < 4; ++j) {
            int n = n0 + tx * 4 + j;
            float vv = acc[i][j];
            if (bias) vv += bias[n];
            if (dogelu) {
                float u = 0.7978845608028654f * (vv + 0.044715f * vv * vv * vv);
                vv = 0.5f * vv * (1.f + tanhf(u));
            }
            if (R) vv += R[(size_t)m * N + n];
            Cm[(size_t)m * N + n] = vv;
        }
    }
}

// ============================================================
// bf16x3 split-precision MFMA GEMM (on-the-fly conversion):
// C = A @ B (+bias) (gelu?) (+residual), fp32 in/out.
// 128x128 tile, BK=32, 4 waves (2x2), mfma_f32_16x16x32_bf16.
// Requires M%128==0 (from mbase), N%128==0, K%32==0.
// ============================================================
__global__ __launch_bounds__(256) void gemm_mfma3_kernel(const float* __restrict__ A,
                                                         const float* __restrict__ Bm,
                                                         const float* __restrict__ bias,
                                                         const float* __restrict__ R,
                                                         float* __restrict__ Cm,
                                                         int M, int N, int K,
                                                         int dogelu, int mbase) {
    __shared__ unsigned short Ah[128][40], Al[128][40];   // [m][k], k contiguous
    __shared__ unsigned short Bh[128][40], Bl[128][40];   // [n][k], k contiguous
    int tid = threadIdx.x;
    int m0 = mbase + (blockIdx.y << 7), n0 = blockIdx.x << 7;
    int lane = tid & 63, wid = tid >> 6;
    int wm = wid >> 1, wn = wid & 1;      // 2x2 wave grid, wave tile 64x64
    int lr = lane & 15, lg = lane >> 4;   // fragment row/col & k-group

    f32x4 acc[4][4] = {};

    int aRow = tid >> 3;               // 0..31 (x4 passes -> 128 rows)
    int aK4  = (tid & 7) << 2;         // k offset 0..28 step 4
    int bN   = tid & 127;              // 0..127
    int bK0  = (tid >> 7) << 4;        // 0 or 16

    for (int k0 = 0; k0 < K; k0 += 32) {
#pragma unroll
        for (int rp = 0; rp < 4; ++rp) {
            int row = aRow + rp * 32;
            float4 a4 = *(const float4*)(A + (size_t)(m0 + row) * K + k0 + aK4);
            float f[4] = {a4.x, a4.y, a4.z, a4.w};
            us4 h4, l4;
#pragma unroll
            for (int c = 0; c < 4; ++c) {
                unsigned short h = f2bf(f[c]);
                h4[c] = h;
                l4[c] = f2bf(f[c] - bf2f(h));
            }
            *(us4*)(&Ah[row][aK4]) = h4;
            *(us4*)(&Al[row][aK4]) = l4;
        }
        {
            unsigned short hb[16], lb[16];
#pragma unroll
            for (int j = 0; j < 16; ++j) {
                float f = Bm[(size_t)(k0 + bK0 + j) * N + n0 + bN];
                unsigned short h = f2bf(f);
                hb[j] = h;
                lb[j] = f2bf(f - bf2f(h));
            }
#pragma unroll
            for (int q = 0; q < 4; ++q) {
                us4 h4, l4;
#pragma unroll
                for (int c = 0; c < 4; ++c) { h4[c] = hb[q * 4 + c]; l4[c] = lb[q * 4 + c]; }
                *(us4*)(&Bh[bN][bK0 + q * 4]) = h4;
                *(us4*)(&Bl[bN][bK0 + q * 4]) = l4;
            }
        }
        __syncthreads();
        bf16x8 fah[4], fal[4], fbh[4], fbl[4];
#pragma unroll
        for (int i = 0; i < 4; ++i) {
            fah[i] = *(const bf16x8*)(&Ah[wm * 64 + i * 16 + lr][lg * 8]);
            fal[i] = *(const bf16x8*)(&Al[wm * 64 + i * 16 + lr][lg * 8]);
            fbh[i] = *(const bf16x8*)(&Bh[wn * 64 + i * 16 + lr][lg * 8]);
            fbl[i] = *(const bf16x8*)(&Bl[wn * 64 + i * 16 + lr][lg * 8]);
        }
#pragma unroll
        for (int i = 0; i < 4; ++i)
#pragma unroll
            for (int j = 0; j < 4; ++j) {
                acc[i][j] = __builtin_amdgcn_mfma_f32_16x16x32_bf16(fah[i], fbh[j], acc[i][j], 0, 0, 0);
                acc[i][j] = __builtin_amdgcn_mfma_f32_16x16x32_bf16(fah[i], fbl[j], acc[i][j], 0, 0, 0);
                acc[i][j] = __builtin_amdgcn_mfma_f32_16x16x32_bf16(fal[i], fbh[j], acc[i][j], 0, 0, 0);
            }
        __syncthreads();
    }
#pragma unroll
    for (int j = 0; j < 4; ++j) {
        int col = n0 + wn * 64 + j * 16 + lr;
        float bv = bias ? bias[col] : 0.f;
#pragma unroll
        for (int i = 0; i < 4; ++i) {
            int rowb = m0 + wm * 64 + i * 16 + lg * 4;
#pragma unroll
            for (int r = 0; r < 4; ++r) {
                float vv = acc[i][j][r] + bv;
                if (dogelu) {
                    float u = 0.7978845608028654f * (vv + 0.044715f * vv * vv * vv);
                    vv = 0.5f * vv * (1.f + tanhf(u));
                }
                if (R) vv += R[(size_t)(rowb + r) * N + col];
                Cm[(size_t)(rowb + r) * N + col] = vv;
            }
        }
    }
}

// ============================================================
// LM-head fast GEMM: C[0..3839, 16384] = xn @ Wlm + blm, bf16x3.
// A precomputed as bf16 hi/lo (xnH/xnL). 256x128 tile, BK=32,
// 512 threads (8 waves, 4x2 grid, 64x64 wave tiles).
// ============================================================
__global__ __launch_bounds__(512) void lmhead_kernel(const unsigned short* __restrict__ AHg,
                                                     const unsigned short* __restrict__ ALg,
                                                     const float* __restrict__ Wlm,
                                                     const float* __restrict__ blm,
                                                     float* __restrict__ Cm) {
    __shared__ unsigned short AH[256 * 32], AL[256 * 32];
    __shared__ unsigned short BH[128 * 32], BL[128 * 32];
    int tid = threadIdx.x;
    int lane = tid & 63, wid = tid >> 6;
    int wm = wid >> 1, wn = wid & 1;       // 4x2 wave grid
    int lr = lane & 15, lg = lane >> 4;
    int m0 = blockIdx.y << 8;              // 256-row tiles (rows < 3840)
    int n0 = blockIdx.x << 7;

    f32x4 acc[4][4] = {};

    int arow_in = lane >> 2;
    int aphys   = lane & 3;
    int o0 = wid * 2, o1 = wid * 2 + 1;
    int row0 = o0 * 16 + arow_in;
    int row1 = o1 * 16 + arow_in;
    int s0 = aphys ^ ((row0 >> 1) & 3);
    int s1 = aphys ^ ((row1 >> 1) & 3);
    size_t ga0 = (size_t)(m0 + row0) * 768 + s0 * 8;
    size_t ga1 = (size_t)(m0 + row1) * 768 + s1 * 8;

    int bcol = tid & 127;
    int bsl  = tid >> 7;                   // logical k-slot (8 k's each)
    int bphys = bsl ^ ((bcol >> 1) & 3);
    const size_t bstr = 16384;

    for (int k0 = 0; k0 < 768; k0 += 32) {
        GLOAD_LDS16(AHg + ga0 + k0, &AH[o0 * 512]);
        GLOAD_LDS16(AHg + ga1 + k0, &AH[o1 * 512]);
        GLOAD_LDS16(ALg + ga0 + k0, &AL[o0 * 512]);
        GLOAD_LDS16(ALg + ga1 + k0, &AL[o1 * 512]);
        const float* bp = Wlm + (size_t)(k0 + bsl * 8) * bstr + n0 + bcol;
        float f[8];
#pragma unroll
        for (int j = 0; j < 8; ++j) f[j] = bp[(size_t)j * bstr];
        us8 hv, lv;
#pragma unroll
        for (int j = 0; j < 8; ++j) {
            unsigned short h = f2bf(f[j]);
            hv[j] = h;
            lv[j] = f2bf(f[j] - bf2f(h));
        }
        *(us8*)(&BH[bcol * 32 + bphys * 8]) = hv;
        *(us8*)(&BL[bcol * 32 + bphys * 8]) = lv;
        __syncthreads();
        bf16x8 fah[4], fal[4];
#pragma unroll
        for (int i = 0; i < 4; ++i) {
            int ar = wm * 64 + i * 16 + lr;
            int sa = (lg ^ ((ar >> 1) & 3)) * 8;
            fah[i] = *(const bf16x8*)(&AH[ar * 32 + sa]);
            fal[i] = *(const bf16x8*)(&AL[ar * 32 + sa]);
        }
#pragma unroll
        for (int j = 0; j < 4; ++j) {
            int bc = wn * 64 + j * 16 + lr;
            int sb = (lg ^ ((bc >> 1) & 3)) * 8;
            bf16x8 fbh = *(const bf16x8*)(&BH[bc * 32 + sb]);
            bf16x8 fbl = *(const bf16x8*)(&BL[bc * 32 + sb]);
#pragma unroll
            for (int i = 0; i < 4; ++i) {
                acc[i][j] = __builtin_amdgcn_mfma_f32_16x16x32_bf16(fah[i], fbh, acc[i][j], 0, 0, 0);
                acc[i][j] = __builtin_amdgcn_mfma_f32_16x16x32_bf16(fah[i], fbl, acc[i][j], 0, 0, 0);
                acc[i][j] = __builtin_amdgcn_mfma_f32_16x16x32_bf16(fal[i], fbh, acc[i][j], 0, 0, 0);
            }
        }
        __syncthreads();
    }
#pragma unroll
    for (int j = 0; j < 4; ++j) {
        int col = n0 + wn * 64 + j * 16 + lr;
        float bv = blm[col];
#pragma unroll
        for (int i = 0; i < 4; ++i) {
            int rowb = m0 + wm * 64 + i * 16 + lg * 4;
#pragma unroll
            for (int r = 0; r < 4; ++r)
                Cm[(size_t)(rowb + r) * 16384 + col] = acc[i][j][r] + bv;
        }
    }
}

// ============================================================
// LSH bucketing: rotated = qk . rot ; bucket = argmax([r,-r])
// ============================================================
__global__ void bucket_kernel(const float* __restrict__ qk, const float* __restrict__ rot,
                              int* __restrict__ buckets) {
    int t = blockIdx.x * 256 + threadIdx.x;
    if (t >= kB * kH * kS) return;
    int b = t / (kH * kS);
    int h = (t / kS) % kH;
    int s = t % kS;
    const float* q  = qk + ((size_t)(b * kS + s)) * kD + h * kDH;
    const float* rr = rot + (size_t)h * kDH * kNR;
    float rv[kNR];
    for (int r = 0; r < kNR; ++r) {
        double acc = 0.0;
        for (int d = 0; d < kDH; ++d)
            acc += (double)q[d] * (double)rr[d * kNR + r];
        rv[r] = (float)acc;
    }
    float best = -INFINITY; int bi = 0;
    for (int idx = 0; idx < 2 * kNR; ++idx) {
        float v = (idx < kNR) ? rv[idx] : -rv[idx - kNR];
        if (v > best) { best = v; bi = idx; }   // first occurrence of max
    }
    buckets[t] = bi;
}

// ============================================================
// Stable counting sort of positions by bucket, per (b,h)
// ============================================================
__global__ __launch_bounds__(256) void sort_kernel(const int* __restrict__ buckets,
                                                   int* __restrict__ order) {
    __shared__ int sb[kS];
    __shared__ int hist[kNB];
    __shared__ int offs[kNB];
    int bh = blockIdx.x;
    const int* bk = buckets + (size_t)bh * kS;
    for (int s = threadIdx.x; s < kS; s += 256) sb[s] = bk[s];
    for (int i = threadIdx.x; i < kNB; i += 256) hist[i] = 0;
    __syncthreads();
    for (int s = threadIdx.x; s < kS; s += 256) atomicAdd(&hist[sb[s]], 1);
    __syncthreads();
    if (threadIdx.x == 0) {
        int run = 0;
        for (int k = 0; k < kNB; ++k) { offs[k] = run; run += hist[k]; }
    }
    __syncthreads();
    for (int s = threadIdx.x; s < kS; s += 256) {
        int bkt = sb[s];
        int cnt = 0;
        for (int t = 0; t < s; ++t) cnt += (sb[t] == bkt) ? 1 : 0;
        order[(size_t)bh * kS + offs[bkt] + cnt] = s;
    }
}

// ============================================================
// Gather sorted qk/v, L2-normalize keys, gather buckets & mask.
// ============================================================
__global__ __launch_bounds__(256) void gather_kernel(const float* __restrict__ qk,
                                                     const float* __restrict__ v,
                                                     const int* __restrict__ buckets,
                                                     const int* __restrict__ amask,
                                                     const int* __restrict__ order,
                                                     float* __restrict__ sqk,
                                                     float* __restrict__ skey,
                                                     float* __restrict__ sv,
                                                     int* __restrict__ sb,
                                                     int* __restrict__ sm) {
    int wid = threadIdx.x >> 6, lane = threadIdx.x & 63;
    int i = blockIdx.x * 4 + wid;         // flat (b*H+h)*S + is
    int b  = i / (kH * kS);
    int h  = (i / kS) % kH;
    int j  = order[i];
    size_t src = ((size_t)(b * kS + j)) * kD + h * kDH + lane;
    float qv = qk[src];
    float vv = v[src];
    float ss = qv * qv;
    for (int m = 32; m >= 1; m >>= 1) ss += __shfl_xor(ss, m, 64);
    float nrm = sqrtf(ss) + 1e-6f;
    size_t o = (size_t)i * kDH + lane;
    sqk[o]  = qv;
    skey[o] = qv / nrm;
    sv[o]   = vv;
    if (lane == 0) {
        sb[i] = buckets[(size_t)(b * kH + h) * kS + j];
        sm[i] = amask[b * kS + j];
    }
}

// ============================================================
// Chunked LSH attention with 1-chunk lookback (wrapping).
// PV: loads are hoisted unconditionally in groups of 8 (pipelined);
// the conditional ADD structure of the verified round-2 kernel is
// kept EXACTLY (same terms, same order -> bit-identical output).
// ============================================================
__global__ __launch_bounds__(256) void attn_kernel(const float* __restrict__ sqk,
                                                   const float* __restrict__ skey,
                                                   const float* __restrict__ sv,
                                                   const int* __restrict__ sb,
                                                   const int* __restrict__ sm,
                                                   const int* __restrict__ order,
                                                   float* __restrict__ aout) {
    __shared__ float ke[2 * kC][kDH + 1];
    __shared__ float qc[kC][kDH];
    __shared__ int bc[kC], icc[kC], be[2 * kC], me[2 * kC], ie[2 * kC];
    int idx = blockIdx.x;
    int b = idx / (kH * kNC);
    int h = (idx / kNC) % kH;
    int n = idx % kNC;
    int prev = (n + kNC - 1) % kNC;
    size_t bhrow = (size_t)(b * kH + h) * kS;
    size_t kbase = bhrow * kDH;
    int tid = threadIdx.x;
    for (int t = tid; t < 2 * kC * kDH; t += 256) {
        int k = t >> 6, d = t & 63;
        int chunk = (k < kC) ? prev : n;
        int krow  = (k < kC) ? k : k - kC;
        ke[k][d] = skey[kbase + ((size_t)(chunk * kC + krow)) * kDH + d];
    }
    for (int t = tid; t < kC * kDH; t += 256) {
        int c = t >> 6, d = t & 63;
        qc[c][d] = sqk[kbase + ((size_t)(n * kC + c)) * kDH + d];
    }
    if (tid < kC) {
        bc[tid]  = sb[bhrow + n * kC + tid];
        icc[tid] = order[bhrow + n * kC + tid];
    }
    for (int t = tid; t < 2 * kC; t += 256) {
        int chunk = (t < kC) ? prev : n;
        int krow  = (t < kC) ? t : t - kC;
        be[t] = sb[bhrow + chunk * kC + krow];
        me[t] = sm[bhrow + chunk * kC + krow];
        ie[t] = order[bhrow + chunk * kC + krow];
    }
    __syncthreads();
    int wid = tid >> 6, lane = tid & 63;
    const float* vprev = sv + kbase + (size_t)prev * kC * kDH;
    const float* vcur  = sv + kbase + (size_t)n * kC * kDH;
    for (int it = 0; it < kC / 4; ++it) {
        int c = it * 4 + wid;
        int col0 = lane, col1 = kC + lane;
        float d0 = 0.f, d1 = 0.f;
#pragma unroll 8
        for (int d = 0; d < kDH; ++d) {
            float q = qc[c][d];
            d0 += q * ke[col0][d];
            d1 += q * ke[col1][d];
        }
        float v0 = d0 * 0.125f, v1 = d1 * 0.125f;   // / sqrt(64)
        int bcc = bc[c], icv = icc[c];
        if (bcc != be[col0] || me[col0] <= 0) v0 = -1e9f;
        if (bcc != be[col1] || me[col1] <= 0) v1 = -1e9f;
        if (icv == ie[col0]) v0 = -1e5f;            // self-mask last (overrides)
        if (icv == ie[col1]) v1 = -1e5f;
        float mx = fmaxf(v0, v1);
        for (int m = 32; m >= 1; m >>= 1) mx = fmaxf(mx, __shfl_xor(mx, m, 64));
        float e0 = expf(v0 - mx), e1 = expf(v1 - mx);
        float sum = e0 + e1;
        for (int m = 32; m >= 1; m >>= 1) sum += __shfl_xor(sum, m, 64);
        float p0 = e0 / sum, p1 = e1 / sum;
        float acc = 0.f;
        for (int kb = 0; kb < kC; kb += 8) {
            float aa[8], vv[8];
#pragma unroll
            for (int j = 0; j < 8; ++j) {
                aa[j] = __shfl(p0, kb + j, 64);                 // uniform broadcast
                vv[j] = vprev[(size_t)(kb + j) * kDH + lane];   // unconditional load
            }
#pragma unroll
            for (int j = 0; j < 8; ++j)
                if (aa[j] != 0.f) acc += aa[j] * vv[j];         // round-2 semantics
        }
        for (int kb = 0; kb < kC; kb += 8) {
            float aa[8], vv[8];
#pragma unroll
            for (int j = 0; j < 8; ++j) {
                aa[j] = __shfl(p1, kb + j, 64);
                vv[j] = vcur[(size_t)(kb + j) * kDH + lane];
            }
#pragma unroll
            for (int j = 0; j < 8; ++j)
                if (aa[j] != 0.f) acc += aa[j] * vv[j];
        }
        aout[((size_t)(b * kS + icv)) * kD + h * kDH + lane] = acc;  // scatter = unsort
    }
}

// ============================================================
// host launcher
// ============================================================
extern "C" void kernel_launch(void* const* d_in, const int* in_sizes, int n_in,
                              void* d_out, int out_size, void* d_ws, size_t ws_size,
                              hipStream_t stream) {
    const int*   ids   = (const int*)d_in[0];
    const int*   amask = (const int*)d_in[1];
    const float* emb   = (const float*)d_in[2];
    const float* pos   = (const float*)d_in[3];
    const float* rot   = (const float*)d_in[4];
    const float* Wqk   = (const float*)d_in[5];
    const float* Wv    = (const float*)d_in[6];
    const float* Wo    = (const float*)d_in[7];
    const float* ln1g  = (const float*)d_in[8];
    const float* ln1b  = (const float*)d_in[9];
    const float* ln2g  = (const float*)d_in[10];
    const float* ln2b  = (const float*)d_in[11];
    const float* W1    = (const float*)d_in[12];
    const float* b1    = (const float*)d_in[13];
    const float* W2    = (const float*)d_in[14];
    const float* b2    = (const float*)d_in[15];
    const float* lnfg  = (const float*)d_in[16];
    const float* lnfb  = (const float*)d_in[17];
    const float* Wlm   = (const float*)d_in[18];
    const float* blm   = (const float*)d_in[19];
    float* out = (float*)d_out;

    const size_t NX  = (size_t)kB * kS * kD;    // 3,145,728 floats
    const size_t NBH = (size_t)kB * kH * kS;    // 49,152
    const size_t NOUT = (size_t)kB * kS * kV;   // 67,108,864 floats (full out)

    // Large fp32 scratch lives in d_out. Layout (floats):
    //   [0,NX) x  [NX,2NX) qk  [2NX,3NX) v  [3NX,4NX) sqk  [4NX,5NX) skey
    //   [5NX,6NX) sv  [6NX,7NX) aoutb  [7NX,11NX) h1
    //   [NOUT-NX, NOUT): xnH/xnL bf16 split of xn (out rows 3904..4095;
    //   fast LM-head writes rows < 3840; rows 3840..4095 done afterwards
    //   by the on-the-fly fallback kernel -> no race).
    float* x     = out;            // [B,S,D]
    float* qk    = out + 1 * NX;
    float* v     = out + 2 * NX;
    float* sqk   = out + 3 * NX;
    float* skey  = out + 4 * NX;
    float* sv    = out + 5 * NX;
    float* aoutb = out + 6 * NX;
    float* h1    = out + 7 * NX;   // [B,S,F] = 4*NX
    unsigned short* xnH = (unsigned short*)(out + NOUT - NX);
    unsigned short* xnL = xnH + NX;          // NX bf16 each = NX floats total
    float* xn    = (float*)d_ws;   // layernorm output [B,S,D]
    int* ibase   = (int*)((float*)d_ws + NX);
    int* buckets = ibase;
    int* order   = ibase + NBH;
    int* sb      = ibase + 2 * NBH;
    int* smv     = ibase + 3 * NBH;

    const int rows = kB * kS;  // 4096

    embed_kernel<<<rows, 256, 0, stream>>>(ids, emb, pos, x);

    for (int l = 0; l < kL; ++l) {
        ln_kernel<<<rows, 256, 0, stream>>>(x, ln1g + l * kD, ln1b + l * kD, xn);
        // Wqk always fp32: feeds bucket argmax (precision-critical)
        gemm_kernel<<<dim3(kD / 64, rows / 64), 256, 0, stream>>>(
            xn, Wqk + (size_t)l * kD * kD, nullptr, nullptr, qk, rows, kD, kD, 0);
        if (l == kL - 1) {
            // post-last-bucketing value path: bf16x3 MFMA is bucket-safe
            gemm_mfma3_kernel<<<dim3(kD / 128, rows / 128), 256, 0, stream>>>(
                xn, Wv + (size_t)l * kD * kD, nullptr, nullptr, v, rows, kD, kD, 0, 0);
        } else {
            gemm_kernel<<<dim3(kD / 64, rows / 64), 256, 0, stream>>>(
                xn, Wv + (size_t)l * kD * kD, nullptr, nullptr, v, rows, kD, kD, 0);
        }
        bucket_kernel<<<(kB * kH * kS) / 256, 256, 0, stream>>>(
            qk, rot + (size_t)l * kH * kDH * kNR, buckets);
        sort_kernel<<<kB * kH, 256, 0, stream>>>(buckets, order);
        gather_kernel<<<(kB * kH * kS) / 4, 256, 0, stream>>>(
            qk, v, buckets, amask, order, sqk, skey, sv, sb, smv);
        attn_kernel<<<kB * kH * kNC, 256, 0, stream>>>(
            sqk, skey, sv, sb, smv, order, aoutb);
        if (l == kL - 1) {
            gemm_mfma3_kernel<<<dim3(kD / 128, rows / 128), 256, 0, stream>>>(
                aoutb, Wo + (size_t)l * kD * kD, nullptr, x, x, rows, kD, kD, 0, 0);
            ln_kernel<<<rows, 256, 0, stream>>>(x, ln2g + l * kD, ln2b + l * kD, xn);
            gemm_mfma3_kernel<<<dim3(kF / 128, rows / 128), 256, 0, stream>>>(
                xn, W1 + (size_t)l * kD * kF, b1 + (size_t)l * kF, nullptr, h1, rows, kF, kD, 1, 0);
            gemm_mfma3_kernel<<<dim3(kD / 128, rows / 128), 256, 0, stream>>>(
                h1, W2 + (size_t)l * kF * kD, b2 + (size_t)l * kD, x, x, rows, kD, kF, 0, 0);
        } else {
            gemm_kernel<<<dim3(kD / 64, rows / 64), 256, 0, stream>>>(
                aoutb, Wo + (size_t)l * kD * kD, nullptr, x, x, rows, kD, kD, 0);
            ln_kernel<<<rows, 256, 0, stream>>>(x, ln2g + l * kD, ln2b + l * kD, xn);
            // layer-0 FFN: A/B test. W1 on new 128x64/8x4 kernel (1536 blocks),
            // W2 on proven 64x64 kernel (768 blocks). Both bit-identical fp32.
            gemm_v2_kernel<<<dim3(kF / 64, rows / 128), 256, 0, stream>>>(
                xn, W1 + (size_t)l * kD * kF, b1 + (size_t)l * kF, nullptr, h1, rows, kF, kD, 1);
            gemm_kernel<<<dim3(kD / 64, rows / 64), 256, 0, stream>>>(
                h1, W2 + (size_t)l * kF * kD, b2 + (size_t)l * kD, x, x, rows, kD, kF, 0);
        }
    }

    ln_kernel<<<rows, 256, 0, stream>>>(x, lnfg, lnfb, xn);
    // Split xn into bf16 hi/lo once (kills A-side conversion redundancy x128)
    convsplit_kernel<<<(int)(NX / 4 / 256), 256, 0, stream>>>(xn, xnH, xnL, (int)(NX / 4));
    // Fast LM head for rows 0..3839
    lmhead_kernel<<<dim3(kV / 128, 3840 / 256), 512, 0, stream>>>(xnH, xnL, Wlm, blm, out);
    // Remaining rows 3840..4095 (runs after fast kernel -> safe to overwrite
    // the bf16 staging region)
    gemm_mfma3_kernel<<<dim3(kV / 128, 2), 256, 0, stream>>>(
        xn, Wlm, blm, nullptr, out, rows, kV, kD, 0, 3840);
}

// Round 6
// 2768.492 us; speedup vs baseline: 1.6496x; 1.0315x over previous
//
#include <hip/hip_runtime.h>
#include <math.h>

// ---- problem constants ----
constexpr int kV  = 16384;
constexpr int kD  = 768;
constexpr int kH  = 12;
constexpr int kDH = 64;
constexpr int kL  = 2;
constexpr int kF  = 3072;
constexpr int kC  = 64;     // chunk length
constexpr int kNR = 32;     // NB/2 rotations
constexpr int kNB = 64;     // number of buckets
constexpr int kB  = 2;
constexpr int kS  = 2048;
constexpr int kNC = kS / kC;  // 32 chunks

typedef __attribute__((ext_vector_type(8))) short bf16x8;
typedef __attribute__((ext_vector_type(4))) float f32x4;
typedef __attribute__((ext_vector_type(4))) unsigned short us4;
typedef __attribute__((ext_vector_type(8))) unsigned short us8;

__device__ __forceinline__ unsigned short f2bf(float f) {
    unsigned u = __float_as_uint(f);
    u += 0x7fffu + ((u >> 16) & 1u);      // round-to-nearest-even
    return (unsigned short)(u >> 16);
}
__device__ __forceinline__ float bf2f(unsigned short h) {
    return __uint_as_float(((unsigned)h) << 16);
}

#define GLOAD_LDS16(gp, lp) __builtin_amdgcn_global_load_lds( \
    (const __attribute__((address_space(1))) unsigned int*)(gp), \
    (__attribute__((address_space(3))) unsigned int*)(lp), 16, 0, 0)

// ============================================================
// x = emb[ids] + pos_emb
// ============================================================
__global__ void embed_kernel(const int* __restrict__ ids, const float* __restrict__ emb,
                             const float* __restrict__ pos, float* __restrict__ x) {
    int row = blockIdx.x;            // b*S + s
    int s = row % kS;
    int id = ids[row];
    for (int d = threadIdx.x; d < kD; d += blockDim.x)
        x[(size_t)row * kD + d] = emb[(size_t)id * kD + d] + pos[(size_t)s * kD + d];
}

// ============================================================
// LayerNorm: y = (x-m)/sqrt(var+1e-12)*g + b   (row = 768)
// ============================================================
__global__ __launch_bounds__(256) void ln_kernel(const float* __restrict__ X,
                                                 const float* __restrict__ g,
                                                 const float* __restrict__ b,
                                                 float* __restrict__ Y) {
    int row = blockIdx.x;
    size_t base = (size_t)row * kD;
    int tid = threadIdx.x;
    float vals[3];
    float s = 0.f, s2 = 0.f;
    int i = 0;
    for (int d = tid; d < kD; d += 256, ++i) {
        float v = X[base + d];
        vals[i] = v; s += v; s2 += v * v;
    }
    for (int m = 32; m >= 1; m >>= 1) {
        s  += __shfl_xor(s,  m, 64);
        s2 += __shfl_xor(s2, m, 64);
    }
    __shared__ float red[2][4];
    int wid = tid >> 6, lane = tid & 63;
    if (lane == 0) { red[0][wid] = s; red[1][wid] = s2; }
    __syncthreads();
    float ts  = red[0][0] + red[0][1] + red[0][2] + red[0][3];
    float ts2 = red[1][0] + red[1][1] + red[1][2] + red[1][3];
    float mean = ts / kD;
    float var  = ts2 / kD - mean * mean;
    float rstd = 1.0f / sqrtf(var + 1e-12f);
    i = 0;
    for (int d = tid; d < kD; d += 256, ++i)
        Y[base + d] = (vals[i] - mean) * rstd * g[d] + b[d];
}

// ============================================================
// fp32 -> bf16 hi/lo split (elementwise, float4 per thread)
// ============================================================
__global__ __launch_bounds__(256) void convsplit_kernel(const float* __restrict__ X,
                                                        unsigned short* __restrict__ H,
                                                        unsigned short* __restrict__ L,
                                                        int n4) {
    int i = blockIdx.x * 256 + threadIdx.x;
    if (i >= n4) return;
    float4 f4 = ((const float4*)X)[i];
    float f[4] = {f4.x, f4.y, f4.z, f4.w};
    us4 h4, l4;
#pragma unroll
    for (int c = 0; c < 4; ++c) {
        unsigned short h = f2bf(f[c]);
        h4[c] = h;
        l4[c] = f2bf(f[c] - bf2f(h));
    }
    ((us4*)H)[i] = h4;
    ((us4*)L)[i] = l4;
}

// ============================================================
// Generic SGEMM: C[M,N] = A[M,K] @ B[K,N] (+bias) (gelu?) (+residual)
// 64x64 tile / block(256), 4x4 micro-tile, K-step 16.
// Register double-buffered: next K-tile loads issue before compute,
// hiding global latency. FMA order unchanged -> bit-identical.
// ============================================================
__global__ __launch_bounds__(256) void gemm_kernel(const float* __restrict__ A,
                                                   const float* __restrict__ Bm,
                                                   const float* __restrict__ bias,
                                                   const float* __restrict__ R,
                                                   float* __restrict__ Cm,
                                                   int M, int N, int K, int dogelu) {
    __shared__ float As[16][68];   // [kk][m], padded row -> 16B aligned
    __shared__ float Bs[16][68];   // [kk][n]
    int tid = threadIdx.x;
    int tx = tid & 15, ty = tid >> 4;
    int m0 = blockIdx.y << 6, n0 = blockIdx.x << 6;
    float acc[4][4] = {{0.f}};
    int aM = tid >> 2;             // (tid*4)/16
    int aK = (tid & 3) << 2;       // (tid*4)%16
    int bK = tid >> 4;             // (tid*4)/64
    int bN = (tid & 15) << 2;      // (tid*4)%64
    const float* aptr = A + (size_t)(m0 + aM) * K + aK;
    const float* bptr = Bm + (size_t)bK * N + n0 + bN;
    float4 a4 = *(const float4*)(aptr);
    float4 b4 = *(const float4*)(bptr);
    for (int k0 = 0; k0 < K; k0 += 16) {
        As[aK + 0][aM] = a4.x; As[aK + 1][aM] = a4.y;
        As[aK + 2][aM] = a4.z; As[aK + 3][aM] = a4.w;
        Bs[bK][bN + 0] = b4.x; Bs[bK][bN + 1] = b4.y;
        Bs[bK][bN + 2] = b4.z; Bs[bK][bN + 3] = b4.w;
        __syncthreads();
        int kn = (k0 + 16 < K) ? (k0 + 16) : k0;   // last iter: dummy reload
        float4 a4n = *(const float4*)(aptr + kn);
        float4 b4n = *(const float4*)(bptr + (size_t)kn * N);
#pragma unroll
        for (int kk = 0; kk < 16; ++kk) {
            float a[4], bb[4];
#pragma unroll
            for (int i = 0; i < 4; ++i) a[i] = As[kk][ty * 4 + i];
#pragma unroll
            for (int j = 0; j < 4; ++j) bb[j] = Bs[kk][tx * 4 + j];
#pragma unroll
            for (int i = 0; i < 4; ++i)
#pragma unroll
                for (int j = 0; j < 4; ++j)
                    acc[i][j] += a[i] * bb[j];
        }
        __syncthreads();
        a4 = a4n; b4 = b4n;
    }
#pragma unroll
    for (int i = 0; i < 4; ++i) {
        int m = m0 + ty * 4 + i;
#pragma unroll
        for (int j = 0; j < 4; ++j) {
            int n = n0 + tx * 4 + j;
            float vv = acc[i][j];
            if (bias) vv += bias[n];
            if (dogelu) {
                float u = 0.7978845608028654f * (vv + 0.044715f * vv * vv * vv);
                vv = 0.5f * vv * (1.f + tanhf(u));
            }
            if (R) vv += R[(size_t)m * N + n];
            Cm[(size_t)m * N + n] = vv;
        }
    }
}

// ============================================================
// fp32 SGEMM v2: 128x64 tile / block(256), 8x4 micro-tile,
// K-step 16, register double-buffered. Bit-identical k-order.
// Requires M%128==0, N%64==0, K%16==0.
// ============================================================
__global__ __launch_bounds__(256) void gemm_v2_kernel(const float* __restrict__ A,
                                                      const float* __restrict__ Bm,
                                                      const float* __restrict__ bias,
                                                      const float* __restrict__ R,
                                                      float* __restrict__ Cm,
                                                      int M, int N, int K, int dogelu) {
    __shared__ float As[16][132];  // [kk][m]
    __shared__ float Bs[16][68];   // [kk][n]
    int tid = threadIdx.x;
    int tx = tid & 15, ty = tid >> 4;       // 16x16 grid: ty->8 rows, tx->4 cols
    int m0 = blockIdx.y << 7, n0 = blockIdx.x << 6;
    float acc[8][4] = {{0.f}};
    int aR = tid >> 1;             // 0..127  (A row)
    int aC = (tid & 1) << 3;       // 0 or 8  (A k-offset)
    int bK = tid >> 4;             // 0..15   (B k row)
    int bN = (tid & 15) << 2;      // 0..60   (B col offset)
    const float* aptr = A + (size_t)(m0 + aR) * K + aC;
    const float* bptr = Bm + (size_t)bK * N + n0 + bN;
    float4 a4 = *(const float4*)(aptr);
    float4 a5 = *(const float4*)(aptr + 4);
    float4 b4 = *(const float4*)(bptr);
    for (int k0 = 0; k0 < K; k0 += 16) {
        As[aC + 0][aR] = a4.x; As[aC + 1][aR] = a4.y;
        As[aC + 2][aR] = a4.z; As[aC + 3][aR] = a4.w;
        As[aC + 4][aR] = a5.x; As[aC + 5][aR] = a5.y;
        As[aC + 6][aR] = a5.z; As[aC + 7][aR] = a5.w;
        *(float4*)(&Bs[bK][bN]) = b4;
        __syncthreads();
        int kn = (k0 + 16 < K) ? (k0 + 16) : k0;
        float4 a4n = *(const float4*)(aptr + kn);
        float4 a5n = *(const float4*)(aptr + kn + 4);
        float4 b4n = *(const float4*)(bptr + (size_t)kn * N);
#pragma unroll
        for (int kk = 0; kk < 16; ++kk) {
            float a[8], bb[4];
#pragma unroll
            for (int i = 0; i < 8; ++i) a[i] = As[kk][ty * 8 + i];
#pragma unroll
            for (int j = 0; j < 4; ++j) bb[j] = Bs[kk][tx * 4 + j];
#pragma unroll
            for (int i = 0; i < 8; ++i)
#pragma unroll
                for (int j = 0; j < 4; ++j)
                    acc[i][j] += a[i] * bb[j];
        }
        __syncthreads();
        a4 = a4n; a5 = a5n; b4 = b4n;
    }
#pragma unroll
    for (int i = 0; i < 8; ++i) {
        int m = m0 + ty * 8 + i;
#pragma unroll
        for (int j = 0; j < 4; ++j) {
            int n = n0 + tx * 4 + j;
            float vv = acc[i][j];
            if (bias) vv += bias[n];
            if (dogelu) {
                float u = 0.7978845608028654f * (vv + 0.044715f * vv * vv * vv);
                vv = 0.5f * vv * (1.f + tanhf(u));
            }
            if (R) vv += R[(size_t)m * N + n];
            Cm[(size_t)m * N + n] = vv;
        }
    }
}

// ============================================================
// bf16x3 split-precision MFMA GEMM (on-the-fly conversion):
// C = A @ B (+bias) (gelu?) (+residual), fp32 in/out.
// 128x128 tile, BK=32, 4 waves (2x2), mfma_f32_16x16x32_bf16.
// Register double-buffered staging loads (same values/order).
// Requires M%128==0 (from mbase), N%128==0, K%32==0.
// ============================================================
__global__ __launch_bounds__(256) void gemm_mfma3_kernel(const float* __restrict__ A,
                                                         const float* __restrict__ Bm,
                                                         const float* __restrict__ bias,
                                                         const float* __restrict__ R,
                                                         float* __restrict__ Cm,
                                                         int M, int N, int K,
                                                         int dogelu, int mbase) {
    __shared__ unsigned short Ah[128][40], Al[128][40];   // [m][k], k contiguous
    __shared__ unsigned short Bh[128][40], Bl[128][40];   // [n][k], k contiguous
    int tid = threadIdx.x;
    int m0 = mbase + (blockIdx.y << 7), n0 = blockIdx.x << 7;
    int lane = tid & 63, wid = tid >> 6;
    int wm = wid >> 1, wn = wid & 1;      // 2x2 wave grid, wave tile 64x64
    int lr = lane & 15, lg = lane >> 4;   // fragment row/col & k-group

    f32x4 acc[4][4] = {};

    int aRow = tid >> 3;               // 0..31 (x4 passes -> 128 rows)
    int aK4  = (tid & 7) << 2;         // k offset 0..28 step 4
    int bN   = tid & 127;              // 0..127
    int bK0  = (tid >> 7) << 4;        // 0 or 16

    float4 pa[4];
    float pb[16];
#pragma unroll
    for (int rp = 0; rp < 4; ++rp)
        pa[rp] = *(const float4*)(A + (size_t)(m0 + aRow + rp * 32) * K + aK4);
#pragma unroll
    for (int j = 0; j < 16; ++j)
        pb[j] = Bm[(size_t)(bK0 + j) * N + n0 + bN];

    for (int k0 = 0; k0 < K; k0 += 32) {
#pragma unroll
        for (int rp = 0; rp < 4; ++rp) {
            int row = aRow + rp * 32;
            float f[4] = {pa[rp].x, pa[rp].y, pa[rp].z, pa[rp].w};
            us4 h4, l4;
#pragma unroll
            for (int c = 0; c < 4; ++c) {
                unsigned short h = f2bf(f[c]);
                h4[c] = h;
                l4[c] = f2bf(f[c] - bf2f(h));
            }
            *(us4*)(&Ah[row][aK4]) = h4;
            *(us4*)(&Al[row][aK4]) = l4;
        }
        {
            unsigned short hb[16], lb[16];
#pragma unroll
            for (int j = 0; j < 16; ++j) {
                unsigned short h = f2bf(pb[j]);
                hb[j] = h;
                lb[j] = f2bf(pb[j] - bf2f(h));
            }
#pragma unroll
            for (int q = 0; q < 4; ++q) {
                us4 h4, l4;
#pragma unroll
                for (int c = 0; c < 4; ++c) { h4[c] = hb[q * 4 + c]; l4[c] = lb[q * 4 + c]; }
                *(us4*)(&Bh[bN][bK0 + q * 4]) = h4;
                *(us4*)(&Bl[bN][bK0 + q * 4]) = l4;
            }
        }
        __syncthreads();
        int kn = (k0 + 32 < K) ? (k0 + 32) : k0;   // last iter: dummy reload
#pragma unroll
        for (int rp = 0; rp < 4; ++rp)
            pa[rp] = *(const float4*)(A + (size_t)(m0 + aRow + rp * 32) * K + kn + aK4);
#pragma unroll
        for (int j = 0; j < 16; ++j)
            pb[j] = Bm[(size_t)(kn + bK0 + j) * N + n0 + bN];
        bf16x8 fah[4], fal[4], fbh[4], fbl[4];
#pragma unroll
        for (int i = 0; i < 4; ++i) {
            fah[i] = *(const bf16x8*)(&Ah[wm * 64 + i * 16 + lr][lg * 8]);
            fal[i] = *(const bf16x8*)(&Al[wm * 64 + i * 16 + lr][lg * 8]);
            fbh[i] = *(const bf16x8*)(&Bh[wn * 64 + i * 16 + lr][lg * 8]);
            fbl[i] = *(const bf16x8*)(&Bl[wn * 64 + i * 16 + lr][lg * 8]);
        }
#pragma unroll
        for (int i = 0; i < 4; ++i)
#pragma unroll
            for (int j = 0; j < 4; ++j) {
                acc[i][j] = __builtin_amdgcn_mfma_f32_16x16x32_bf16(fah[i], fbh[j], acc[i][j], 0, 0, 0);
                acc[i][j] = __builtin_amdgcn_mfma_f32_16x16x32_bf16(fah[i], fbl[j], acc[i][j], 0, 0, 0);
                acc[i][j] = __builtin_amdgcn_mfma_f32_16x16x32_bf16(fal[i], fbh[j], acc[i][j], 0, 0, 0);
            }
        __syncthreads();
    }
#pragma unroll
    for (int j = 0; j < 4; ++j) {
        int col = n0 + wn * 64 + j * 16 + lr;
        float bv = bias ? bias[col] : 0.f;
#pragma unroll
        for (int i = 0; i < 4; ++i) {
            int rowb = m0 + wm * 64 + i * 16 + lg * 4;
#pragma unroll
            for (int r = 0; r < 4; ++r) {
                float vv = acc[i][j][r] + bv;
                if (dogelu) {
                    float u = 0.7978845608028654f * (vv + 0.044715f * vv * vv * vv);
                    vv = 0.5f * vv * (1.f + tanhf(u));
                }
                if (R) vv += R[(size_t)(rowb + r) * N + col];
                Cm[(size_t)(rowb + r) * N + col] = vv;
            }
        }
    }
}

// ============================================================
// LM-head fast GEMM: C[0..3839, 16384] = xn @ Wlm + blm, bf16x3.
// A precomputed as bf16 hi/lo (xnH/xnL). 256x128 tile, BK=32,
// 512 threads (8 waves, 4x2 grid, 64x64 wave tiles).
// ============================================================
__global__ __launch_bounds__(512) void lmhead_kernel(const unsigned short* __restrict__ AHg,
                                                     const unsigned short* __restrict__ ALg,
                                                     const float* __restrict__ Wlm,
                                                     const float* __restrict__ blm,
                                                     float* __restrict__ Cm) {
    __shared__ unsigned short AH[256 * 32], AL[256 * 32];
    __shared__ unsigned short BH[128 * 32], BL[128 * 32];
    int tid = threadIdx.x;
    int lane = tid & 63, wid = tid >> 6;
    int wm = wid >> 1, wn = wid & 1;       // 4x2 wave grid
    int lr = lane & 15, lg = lane >> 4;
    int m0 = blockIdx.y << 8;              // 256-row tiles (rows < 3840)
    int n0 = blockIdx.x << 7;

    f32x4 acc[4][4] = {};

    int arow_in = lane >> 2;
    int aphys   = lane & 3;
    int o0 = wid * 2, o1 = wid * 2 + 1;
    int row0 = o0 * 16 + arow_in;
    int row1 = o1 * 16 + arow_in;
    int s0 = aphys ^ ((row0 >> 1) & 3);
    int s1 = aphys ^ ((row1 >> 1) & 3);
    size_t ga0 = (size_t)(m0 + row0) * 768 + s0 * 8;
    size_t ga1 = (size_t)(m0 + row1) * 768 + s1 * 8;

    int bcol = tid & 127;
    int bsl  = tid >> 7;                   // logical k-slot (8 k's each)
    int bphys = bsl ^ ((bcol >> 1) & 3);
    const size_t bstr = 16384;

    for (int k0 = 0; k0 < 768; k0 += 32) {
        GLOAD_LDS16(AHg + ga0 + k0, &AH[o0 * 512]);
        GLOAD_LDS16(AHg + ga1 + k0, &AH[o1 * 512]);
        GLOAD_LDS16(ALg + ga0 + k0, &AL[o0 * 512]);
        GLOAD_LDS16(ALg + ga1 + k0, &AL[o1 * 512]);
        const float* bp = Wlm + (size_t)(k0 + bsl * 8) * bstr + n0 + bcol;
        float f[8];
#pragma unroll
        for (int j = 0; j < 8; ++j) f[j] = bp[(size_t)j * bstr];
        us8 hv, lv;
#pragma unroll
        for (int j = 0; j < 8; ++j) {
            unsigned short h = f2bf(f[j]);
            hv[j] = h;
            lv[j] = f2bf(f[j] - bf2f(h));
        }
        *(us8*)(&BH[bcol * 32 + bphys * 8]) = hv;
        *(us8*)(&BL[bcol * 32 + bphys * 8]) = lv;
        __syncthreads();
        bf16x8 fah[4], fal[4];
#pragma unroll
        for (int i = 0; i < 4; ++i) {
            int ar = wm * 64 + i * 16 + lr;
            int sa = (lg ^ ((ar >> 1) & 3)) * 8;
            fah[i] = *(const bf16x8*)(&AH[ar * 32 + sa]);
            fal[i] = *(const bf16x8*)(&AL[ar * 32 + sa]);
        }
#pragma unroll
        for (int j = 0; j < 4; ++j) {
            int bc = wn * 64 + j * 16 + lr;
            int sb = (lg ^ ((bc >> 1) & 3)) * 8;
            bf16x8 fbh = *(const bf16x8*)(&BH[bc * 32 + sb]);
            bf16x8 fbl = *(const bf16x8*)(&BL[bc * 32 + sb]);
#pragma unroll
            for (int i = 0; i < 4; ++i) {
                acc[i][j] = __builtin_amdgcn_mfma_f32_16x16x32_bf16(fah[i], fbh, acc[i][j], 0, 0, 0);
                acc[i][j] = __builtin_amdgcn_mfma_f32_16x16x32_bf16(fah[i], fbl, acc[i][j], 0, 0, 0);
                acc[i][j] = __builtin_amdgcn_mfma_f32_16x16x32_bf16(fal[i], fbh, acc[i][j], 0, 0, 0);
            }
        }
        __syncthreads();
    }
#pragma unroll
    for (int j = 0; j < 4; ++j) {
        int col = n0 + wn * 64 + j * 16 + lr;
        float bv = blm[col];
#pragma unroll
        for (int i = 0; i < 4; ++i) {
            int rowb = m0 + wm * 64 + i * 16 + lg * 4;
#pragma unroll
            for (int r = 0; r < 4; ++r)
                Cm[(size_t)(rowb + r) * 16384 + col] = acc[i][j][r] + bv;
        }
    }
}

// ============================================================
// LSH bucketing: rotated = qk . rot ; bucket = argmax([r,-r])
// ============================================================
__global__ void bucket_kernel(const float* __restrict__ qk, const float* __restrict__ rot,
                              int* __restrict__ buckets) {
    int t = blockIdx.x * 256 + threadIdx.x;
    if (t >= kB * kH * kS) return;
    int b = t / (kH * kS);
    int h = (t / kS) % kH;
    int s = t % kS;
    const float* q  = qk + ((size_t)(b * kS + s)) * kD + h * kDH;
    const float* rr = rot + (size_t)h * kDH * kNR;
    float rv[kNR];
    for (int r = 0; r < kNR; ++r) {
        double acc = 0.0;
        for (int d = 0; d < kDH; ++d)
            acc += (double)q[d] * (double)rr[d * kNR + r];
        rv[r] = (float)acc;
    }
    float best = -INFINITY; int bi = 0;
    for (int idx = 0; idx < 2 * kNR; ++idx) {
        float v = (idx < kNR) ? rv[idx] : -rv[idx - kNR];
        if (v > best) { best = v; bi = idx; }   // first occurrence of max
    }
    buckets[t] = bi;
}

// ============================================================
// Stable counting sort of positions by bucket, per (b,h)
// ============================================================
__global__ __launch_bounds__(256) void sort_kernel(const int* __restrict__ buckets,
                                                   int* __restrict__ order) {
    __shared__ int sb[kS];
    __shared__ int hist[kNB];
    __shared__ int offs[kNB];
    int bh = blockIdx.x;
    const int* bk = buckets + (size_t)bh * kS;
    for (int s = threadIdx.x; s < kS; s += 256) sb[s] = bk[s];
    for (int i = threadIdx.x; i < kNB; i += 256) hist[i] = 0;
    __syncthreads();
    for (int s = threadIdx.x; s < kS; s += 256) atomicAdd(&hist[sb[s]], 1);
    __syncthreads();
    if (threadIdx.x == 0) {
        int run = 0;
        for (int k = 0; k < kNB; ++k) { offs[k] = run; run += hist[k]; }
    }
    __syncthreads();
    for (int s = threadIdx.x; s < kS; s += 256) {
        int bkt = sb[s];
        int cnt = 0;
        for (int t = 0; t < s; ++t) cnt += (sb[t] == bkt) ? 1 : 0;
        order[(size_t)bh * kS + offs[bkt] + cnt] = s;
    }
}

// ============================================================
// Gather sorted qk/v, L2-normalize keys, gather buckets & mask.
// ============================================================
__global__ __launch_bounds__(256) void gather_kernel(const float* __restrict__ qk,
                                                     const float* __restrict__ v,
                                                     const int* __restrict__ buckets,
                                                     const int* __restrict__ amask,
                                                     const int* __restrict__ order,
                                                     float* __restrict__ sqk,
                                                     float* __restrict__ skey,
                                                     float* __restrict__ sv,
                                                     int* __restrict__ sb,
                                                     int* __restrict__ sm) {
    int wid = threadIdx.x >> 6, lane = threadIdx.x & 63;
    int i = blockIdx.x * 4 + wid;         // flat (b*H+h)*S + is
    int b  = i / (kH * kS);
    int h  = (i / kS) % kH;
    int j  = order[i];
    size_t src = ((size_t)(b * kS + j)) * kD + h * kDH + lane;
    float qv = qk[src];
    float vv = v[src];
    float ss = qv * qv;
    for (int m = 32; m >= 1; m >>= 1) ss += __shfl_xor(ss, m, 64);
    float nrm = sqrtf(ss) + 1e-6f;
    size_t o = (size_t)i * kDH + lane;
    sqk[o]  = qv;
    skey[o] = qv / nrm;
    sv[o]   = vv;
    if (lane == 0) {
        sb[i] = buckets[(size_t)(b * kH + h) * kS + j];
        sm[i] = amask[b * kS + j];
    }
}

// ============================================================
// Chunked LSH attention with 1-chunk lookback (wrapping).
// PV: loads are hoisted unconditionally in groups of 8 (pipelined);
// the conditional ADD structure of the verified round-2 kernel is
// kept EXACTLY (same terms, same order -> bit-identical output).
// ============================================================
__global__ __launch_bounds__(256) void attn_kernel(const float* __restrict__ sqk,
                                                   const float* __restrict__ skey,
                                                   const float* __restrict__ sv,
                                                   const int* __restrict__ sb,
                                                   const int* __restrict__ sm,
                                                   const int* __restrict__ order,
                                                   float* __restrict__ aout) {
    __shared__ float ke[2 * kC][kDH + 1];
    __shared__ float qc[kC][kDH];
    __shared__ int bc[kC], icc[kC], be[2 * kC], me[2 * kC], ie[2 * kC];
    int idx = blockIdx.x;
    int b = idx / (kH * kNC);
    int h = (idx / kNC) % kH;
    int n = idx % kNC;
    int prev = (n + kNC - 1) % kNC;
    size_t bhrow = (size_t)(b * kH + h) * kS;
    size_t kbase = bhrow * kDH;
    int tid = threadIdx.x;
    for (int t = tid; t < 2 * kC * kDH; t += 256) {
        int k = t >> 6, d = t & 63;
        int chunk = (k < kC) ? prev : n;
        int krow  = (k < kC) ? k : k - kC;
        ke[k][d] = skey[kbase + ((size_t)(chunk * kC + krow)) * kDH + d];
    }
    for (int t = tid; t < kC * kDH; t += 256) {
        int c = t >> 6, d = t & 63;
        qc[c][d] = sqk[kbase + ((size_t)(n * kC + c)) * kDH + d];
    }
    if (tid < kC) {
        bc[tid]  = sb[bhrow + n * kC + tid];
        icc[tid] = order[bhrow + n * kC + tid];
    }
    for (int t = tid; t < 2 * kC; t += 256) {
        int chunk = (t < kC) ? prev : n;
        int krow  = (t < kC) ? t : t - kC;
        be[t] = sb[bhrow + chunk * kC + krow];
        me[t] = sm[bhrow + chunk * kC + krow];
        ie[t] = order[bhrow + chunk * kC + krow];
    }
    __syncthreads();
    int wid = tid >> 6, lane = tid & 63;
    const float* vprev = sv + kbase + (size_t)prev * kC * kDH;
    const float* vcur  = sv + kbase + (size_t)n * kC * kDH;
    for (int it = 0; it < kC / 4; ++it) {
        int c = it * 4 + wid;
        int col0 = lane, col1 = kC + lane;
        float d0 = 0.f, d1 = 0.f;
#pragma unroll 8
        for (int d = 0; d < kDH; ++d) {
            float q = qc[c][d];
            d0 += q * ke[col0][d];
            d1 += q * ke[col1][d];
        }
        float v0 = d0 * 0.125f, v1 = d1 * 0.125f;   // / sqrt(64)
        int bcc = bc[c], icv = icc[c];
        if (bcc != be[col0] || me[col0] <= 0) v0 = -1e9f;
        if (bcc != be[col1] || me[col1] <= 0) v1 = -1e9f;
        if (icv == ie[col0]) v0 = -1e5f;            // self-mask last (overrides)
        if (icv == ie[col1]) v1 = -1e5f;
        float mx = fmaxf(v0, v1);
        for (int m = 32; m >= 1; m >>= 1) mx = fmaxf(mx, __shfl_xor(mx, m, 64));
        float e0 = expf(v0 - mx), e1 = expf(v1 - mx);
        float sum = e0 + e1;
        for (int m = 32; m >= 1; m >>= 1) sum += __shfl_xor(sum, m, 64);
        float p0 = e0 / sum, p1 = e1 / sum;
        float acc = 0.f;
        for (int kb = 0; kb < kC; kb += 8) {
            float aa[8], vv[8];
#pragma unroll
            for (int j = 0; j < 8; ++j) {
                aa[j] = __shfl(p0, kb + j, 64);                 // uniform broadcast
                vv[j] = vprev[(size_t)(kb + j) * kDH + lane];   // unconditional load
            }
#pragma unroll
            for (int j = 0; j < 8; ++j)
                if (aa[j] != 0.f) acc += aa[j] * vv[j];         // round-2 semantics
        }
        for (int kb = 0; kb < kC; kb += 8) {
            float aa[8], vv[8];
#pragma unroll
            for (int j = 0; j < 8; ++j) {
                aa[j] = __shfl(p1, kb + j, 64);
                vv[j] = vcur[(size_t)(kb + j) * kDH + lane];
            }
#pragma unroll
            for (int j = 0; j < 8; ++j)
                if (aa[j] != 0.f) acc += aa[j] * vv[j];
        }
        aout[((size_t)(b * kS + icv)) * kD + h * kDH + lane] = acc;  // scatter = unsort
    }
}

// ============================================================
// host launcher
// ============================================================
extern "C" void kernel_launch(void* const* d_in, const int* in_sizes, int n_in,
                              void* d_out, int out_size, void* d_ws, size_t ws_size,
                              hipStream_t stream) {
    const int*   ids   = (const int*)d_in[0];
    const int*   amask = (const int*)d_in[1];
    const float* emb   = (const float*)d_in[2];
    const float* pos   = (const float*)d_in[3];
    const float* rot   = (const float*)d_in[4];
    const float* Wqk   = (const float*)d_in[5];
    const float* Wv    = (const float*)d_in[6];
    const float* Wo    = (const float*)d_in[7];
    const float* ln1g  = (const float*)d_in[8];
    const float* ln1b  = (const float*)d_in[9];
    const float* ln2g  = (const float*)d_in[10];
    const float* ln2b  = (const float*)d_in[11];
    const float* W1    = (const float*)d_in[12];
    const float* b1    = (const float*)d_in[13];
    const float* W2    = (const float*)d_in[14];
    const float* b2    = (const float*)d_in[15];
    const float* lnfg  = (const float*)d_in[16];
    const float* lnfb  = (const float*)d_in[17];
    const float* Wlm   = (const float*)d_in[18];
    const float* blm   = (const float*)d_in[19];
    float* out = (float*)d_out;

    const size_t NX  = (size_t)kB * kS * kD;    // 3,145,728 floats
    const size_t NBH = (size_t)kB * kH * kS;    // 49,152
    const size_t NOUT = (size_t)kB * kS * kV;   // 67,108,864 floats (full out)

    // Large fp32 scratch lives in d_out. Layout (floats):
    //   [0,NX) x  [NX,2NX) qk  [2NX,3NX) v  [3NX,4NX) sqk  [4NX,5NX) skey
    //   [5NX,6NX) sv  [6NX,7NX) aoutb  [7NX,11NX) h1
    //   [NOUT-NX, NOUT): xnH/xnL bf16 split of xn (out rows 3904..4095;
    //   fast LM-head writes rows < 3840; rows 3840..4095 done afterwards
    //   by the on-the-fly fallback kernel -> no race).
    float* x     = out;            // [B,S,D]
    float* qk    = out + 1 * NX;
    float* v     = out + 2 * NX;
    float* sqk   = out + 3 * NX;
    float* skey  = out + 4 * NX;
    float* sv    = out + 5 * NX;
    float* aoutb = out + 6 * NX;
    float* h1    = out + 7 * NX;   // [B,S,F] = 4*NX
    unsigned short* xnH = (unsigned short*)(out + NOUT - NX);
    unsigned short* xnL = xnH + NX;          // NX bf16 each = NX floats total
    float* xn    = (float*)d_ws;   // layernorm output [B,S,D]
    int* ibase   = (int*)((float*)d_ws + NX);
    int* buckets = ibase;
    int* order   = ibase + NBH;
    int* sb      = ibase + 2 * NBH;
    int* smv     = ibase + 3 * NBH;

    const int rows = kB * kS;  // 4096

    embed_kernel<<<rows, 256, 0, stream>>>(ids, emb, pos, x);

    for (int l = 0; l < kL; ++l) {
        ln_kernel<<<rows, 256, 0, stream>>>(x, ln1g + l * kD, ln1b + l * kD, xn);
        // Wqk always fp32: feeds bucket argmax (precision-critical)
        gemm_kernel<<<dim3(kD / 64, rows / 64), 256, 0, stream>>>(
            xn, Wqk + (size_t)l * kD * kD, nullptr, nullptr, qk, rows, kD, kD, 0);
        if (l == kL - 1) {
            // post-last-bucketing value path: bf16x3 MFMA is bucket-safe
            gemm_mfma3_kernel<<<dim3(kD / 128, rows / 128), 256, 0, stream>>>(
                xn, Wv + (size_t)l * kD * kD, nullptr, nullptr, v, rows, kD, kD, 0, 0);
        } else {
            gemm_kernel<<<dim3(kD / 64, rows / 64), 256, 0, stream>>>(
                xn, Wv + (size_t)l * kD * kD, nullptr, nullptr, v, rows, kD, kD, 0);
        }
        bucket_kernel<<<(kB * kH * kS) / 256, 256, 0, stream>>>(
            qk, rot + (size_t)l * kH * kDH * kNR, buckets);
        sort_kernel<<<kB * kH, 256, 0, stream>>>(buckets, order);
        gather_kernel<<<(kB * kH * kS) / 4, 256, 0, stream>>>(
            qk, v, buckets, amask, order, sqk, skey, sv, sb, smv);
        attn_kernel<<<kB * kH * kNC, 256, 0, stream>>>(
            sqk, skey, sv, sb, smv, order, aoutb);
        if (l == kL - 1) {
            gemm_mfma3_kernel<<<dim3(kD / 128, rows / 128), 256, 0, stream>>>(
                aoutb, Wo + (size_t)l * kD * kD, nullptr, x, x, rows, kD, kD, 0, 0);
            ln_kernel<<<rows, 256, 0, stream>>>(x, ln2g + l * kD, ln2b + l * kD, xn);
            gemm_mfma3_kernel<<<dim3(kF / 128, rows / 128), 256, 0, stream>>>(
                xn, W1 + (size_t)l * kD * kF, b1 + (size_t)l * kF, nullptr, h1, rows, kF, kD, 1, 0);
            gemm_mfma3_kernel<<<dim3(kD / 128, rows / 128), 256, 0, stream>>>(
                h1, W2 + (size_t)l * kF * kD, b2 + (size_t)l * kD, x, x, rows, kD, kF, 0, 0);
        } else {
            gemm_kernel<<<dim3(kD / 64, rows / 64), 256, 0, stream>>>(
                aoutb, Wo + (size_t)l * kD * kD, nullptr, x, x, rows, kD, kD, 0);
            ln_kernel<<<rows, 256, 0, stream>>>(x, ln2g + l * kD, ln2b + l * kD, xn);
            // layer-0 FFN: W1 on v2 (128x64, 1536 blocks), W2 on 64x64 kernel.
            // Both fp32, bit-identical k-order (bucket-safe).
            gemm_v2_kernel<<<dim3(kF / 64, rows / 128), 256, 0, stream>>>(
                xn, W1 + (size_t)l * kD * kF, b1 + (size_t)l * kF, nullptr, h1, rows, kF, kD, 1);
            gemm_kernel<<<dim3(kD / 64, rows / 64), 256, 0, stream>>>(
                h1, W2 + (size_t)l * kF * kD, b2 + (size_t)l * kD, x, x, rows, kD, kF, 0);
        }
    }

    ln_kernel<<<rows, 256, 0, stream>>>(x, lnfg, lnfb, xn);
    // Split xn into bf16 hi/lo once (kills A-side conversion redundancy x128)
    convsplit_kernel<<<(int)(NX / 4 / 256), 256, 0, stream>>>(xn, xnH, xnL, (int)(NX / 4));
    // Fast LM head for rows 0..3839
    lmhead_kernel<<<dim3(kV / 128, 3840 / 256), 512, 0, stream>>>(xnH, xnL, Wlm, blm, out);
    // Remaining rows 3840..4095 (runs after fast kernel -> safe to overwrite
    // the bf16 staging region)
    gemm_mfma3_kernel<<<dim3(kV / 128, 2), 256, 0, stream>>>(
        xn, Wlm, blm, nullptr, out, rows, kV, kD, 0, 3840);
}